// Round 5
// baseline (4082.254 us; speedup 1.0000x reference)
//
#include <hip/hip_runtime.h>

#define N_NODES 100000
#define N_EDGES 1600000
#define N_GRAPHS 1024
#define HID 128
#define LAYERS 4
#define LN_EPS 1e-5f
#define LPAD (HID + 4)
#define NB_SCAN 391  // ceil(100000/256)

// ---------------- input projection: h = x @ inW + inb ----------------
__global__ __launch_bounds__(256) void k_input_proj(
    const float* __restrict__ x, const float* __restrict__ inW,
    const float* __restrict__ inb, float* __restrict__ h) {
    int idx = blockIdx.x * 256 + threadIdx.x;  // over N_NODES*HID (exact)
    int n = idx >> 7, c = idx & 127;
    const float* xr = x + n * 7;
    float s = inb[c];
#pragma unroll
    for (int k = 0; k < 7; ++k) s += xr[k] * inW[k * HID + c];
    h[idx] = s;
}

// ---------------- CSR build: histogram of dst ------------------------
__global__ __launch_bounds__(256) void k_hist(
    const int* __restrict__ ei, int* __restrict__ deg) {
    int e = blockIdx.x * 256 + threadIdx.x;  // N_EDGES exact
    atomicAdd(&deg[ei[N_EDGES + e]], 1);
}

// ---------------- CSR build: parallel 3-stage scan -------------------
__global__ __launch_bounds__(256) void k_scan1(
    const int* __restrict__ deg, int* __restrict__ bsum) {
    const int i = blockIdx.x * 256 + threadIdx.x;
    int v = (i < N_NODES) ? deg[i] : 0;
#pragma unroll
    for (int off = 1; off < 64; off <<= 1) v += __shfl_xor(v, off);
    __shared__ int wsum[4];
    if ((threadIdx.x & 63) == 0) wsum[threadIdx.x >> 6] = v;
    __syncthreads();
    if (threadIdx.x == 0) bsum[blockIdx.x] = wsum[0] + wsum[1] + wsum[2] + wsum[3];
}

__global__ __launch_bounds__(512) void k_scan2(
    const int* __restrict__ bsum, int* __restrict__ bpre) {
    __shared__ int tmp[512];
    const int t = threadIdx.x;
    int v = (t < NB_SCAN) ? bsum[t] : 0;
    tmp[t] = v;
    __syncthreads();
    for (int off = 1; off < 512; off <<= 1) {
        int u = (t >= off) ? tmp[t - off] : 0;
        __syncthreads();
        tmp[t] += u;
        __syncthreads();
    }
    if (t < NB_SCAN) bpre[t] = tmp[t] - v;  // exclusive
}

__global__ __launch_bounds__(256) void k_scan3(
    const int* __restrict__ deg, const int* __restrict__ bpre,
    int* __restrict__ row_ptr, int* __restrict__ cursor) {
    __shared__ int tmp[256];
    const int t = threadIdx.x;
    const int i = blockIdx.x * 256 + t;
    int d = (i < N_NODES) ? deg[i] : 0;
    tmp[t] = d;
    __syncthreads();
    for (int off = 1; off < 256; off <<= 1) {
        int u = (t >= off) ? tmp[t - off] : 0;
        __syncthreads();
        tmp[t] += u;
        __syncthreads();
    }
    if (i < N_NODES) {
        const int ex = bpre[blockIdx.x] + tmp[t] - d;
        row_ptr[i] = ex;
        cursor[i] = ex;
        if (i == N_NODES - 1) row_ptr[N_NODES] = N_EDGES;
    }
}

// ---------------- CSR build: scatter edges into sorted slots ---------
__global__ __launch_bounds__(256) void k_scatter(
    const int* __restrict__ ei, const float* __restrict__ ea,
    int* __restrict__ cursor, float4* __restrict__ edata) {
    int e = blockIdx.x * 256 + threadIdx.x;  // N_EDGES exact
    const int src = ei[e];
    const int dst = ei[N_EDGES + e];
    const int pos = atomicAdd(&cursor[dst], 1);
    edata[pos] = make_float4(ea[e * 3 + 0], ea[e * 3 + 1], ea[e * 3 + 2],
                             __int_as_float(src));
}

// ------- fused gather-aggregate + MLP + residual + layernorm ---------
// 256 threads = 4 waves; each wave owns 4 nodes end-to-end. The wave's 4
// CSR rows are contiguous -> one merged edge stream, software-pipelined
// with a register double buffer held in NAMED float4 scalars (by-value
// helpers only -- pointer-to-local caused scratch spills in R4).
__global__ __launch_bounds__(256) void k_node_update(
    const float4* __restrict__ edata, const int* __restrict__ row_ptr,
    const float* __restrict__ eW, const float* __restrict__ eb,
    const float* __restrict__ hin, float* __restrict__ hout,
    const float* __restrict__ w1, const float* __restrict__ b1,
    const float* __restrict__ w2, const float* __restrict__ b2,
    const float* __restrict__ gamma, const float* __restrict__ beta) {
    __shared__ float gt[16][LPAD];
    __shared__ float t1[16][LPAD];
    const int wave = threadIdx.x >> 6;
    const int lane = threadIdx.x & 63;
    const int c2 = lane * 2;            // this thread's 2 columns
    const int n0 = blockIdx.x * 16;
    const int r0 = wave * 4;            // this wave's first row slot

    // ---- phase 1: merged-stream gather-aggregate ----
    {
        const float2 ew0 = *(const float2*)(eW + 0 * HID + c2);
        const float2 ew1 = *(const float2*)(eW + 1 * HID + c2);
        const float2 ew2 = *(const float2*)(eW + 2 * HID + c2);
        const float2 ebv = *(const float2*)(eb + c2);
        const int nb = n0 + r0;
        const int rp0 = row_ptr[nb + 0];
        const int rp1 = row_ptr[nb + 1];
        const int rp2 = row_ptr[nb + 2];
        const int rp3 = row_ptr[nb + 3];
        const int rp4 = row_ptr[nb + 4];

        float a0x, a0y, a1x, a1y, a2x, a2y, a3x, a3y;
        { const float2 v = *(const float2*)(hin + (long)(nb + 0) * HID + c2); a0x = v.x; a0y = v.y; }
        { const float2 v = *(const float2*)(hin + (long)(nb + 1) * HID + c2); a1x = v.x; a1y = v.y; }
        { const float2 v = *(const float2*)(hin + (long)(nb + 2) * HID + c2); a2x = v.x; a2y = v.y; }
        { const float2 v = *(const float2*)(hin + (long)(nb + 3) * HID + c2); a3x = v.x; a3y = v.y; }

        auto acc1 = [&](float4 ed, float2 g, int idx) {
            const float mx = fmaxf(g.x + ed.x * ew0.x + ed.y * ew1.x + ed.z * ew2.x + ebv.x, 0.f);
            const float my = fmaxf(g.y + ed.x * ew0.y + ed.y * ew1.y + ed.z * ew2.y + ebv.y, 0.f);
            if (idx < rp1)      { a0x += mx; a0y += my; }
            else if (idx < rp2) { a1x += mx; a1y += my; }
            else if (idx < rp3) { a2x += mx; a2y += my; }
            else                { a3x += mx; a3y += my; }
        };
        auto proc4 = [&](float4 d0, float4 d1, float4 d2, float4 d3, int ebase) {
            const int s0_ = __builtin_amdgcn_readfirstlane(__float_as_int(d0.w));
            const int s1_ = __builtin_amdgcn_readfirstlane(__float_as_int(d1.w));
            const int s2_ = __builtin_amdgcn_readfirstlane(__float_as_int(d2.w));
            const int s3_ = __builtin_amdgcn_readfirstlane(__float_as_int(d3.w));
            const float2 g0 = *(const float2*)(hin + (long)s0_ * HID + c2);
            const float2 g1 = *(const float2*)(hin + (long)s1_ * HID + c2);
            const float2 g2 = *(const float2*)(hin + (long)s2_ * HID + c2);
            const float2 g3 = *(const float2*)(hin + (long)s3_ * HID + c2);
            acc1(d0, g0, ebase + 0);
            acc1(d1, g1, ebase + 1);
            acc1(d2, g2, ebase + 2);
            acc1(d3, g3, ebase + 3);
        };

        float4 A0, A1, A2, A3, B0, B1, B2, B3;
        int e = rp0;
        int rem = rp4 - rp0;
        if (rem >= 4) {
            A0 = edata[e]; A1 = edata[e + 1]; A2 = edata[e + 2]; A3 = edata[e + 3];
        }
        while (rem >= 12) {
            B0 = edata[e + 4]; B1 = edata[e + 5]; B2 = edata[e + 6]; B3 = edata[e + 7];
            proc4(A0, A1, A2, A3, e);
            A0 = edata[e + 8]; A1 = edata[e + 9]; A2 = edata[e + 10]; A3 = edata[e + 11];
            proc4(B0, B1, B2, B3, e + 4);
            e += 8; rem -= 8;
        }
        if (rem >= 8) {
            B0 = edata[e + 4]; B1 = edata[e + 5]; B2 = edata[e + 6]; B3 = edata[e + 7];
            proc4(A0, A1, A2, A3, e);
            proc4(B0, B1, B2, B3, e + 4);
            e += 8; rem -= 8;
        } else if (rem >= 4) {
            proc4(A0, A1, A2, A3, e);
            e += 4; rem -= 4;
        }
        for (; rem > 0; --rem, ++e) {
            const float4 ed = edata[e];
            const int sr = __builtin_amdgcn_readfirstlane(__float_as_int(ed.w));
            const float2 gv = *(const float2*)(hin + (long)sr * HID + c2);
            acc1(ed, gv, e);
        }
        *(float2*)&gt[r0 + 0][c2] = make_float2(a0x, a0y);
        *(float2*)&gt[r0 + 1][c2] = make_float2(a1x, a1y);
        *(float2*)&gt[r0 + 2][c2] = make_float2(a2x, a2y);
        *(float2*)&gt[r0 + 3][c2] = make_float2(a3x, a3y);
    }
    // same-wave LDS producer/consumer: hardware-ordered, no barrier needed

    // ---- phase 2: t1 = relu(gt @ w1 + b1), b128 4-k blocking ----
    {
        float acc[4][2];
        const float2 bv = *(const float2*)(b1 + c2);
#pragma unroll
        for (int r = 0; r < 4; ++r) { acc[r][0] = bv.x; acc[r][1] = bv.y; }
        for (int k4 = 0; k4 < HID; k4 += 4) {
            float4 g4[4];
#pragma unroll
            for (int r = 0; r < 4; ++r) g4[r] = *(const float4*)&gt[r0 + r][k4];
#pragma unroll
            for (int kk = 0; kk < 4; ++kk) {
                const float2 w = *(const float2*)(w1 + (k4 + kk) * HID + c2);
#pragma unroll
                for (int r = 0; r < 4; ++r) {
                    const float gv = ((const float*)&g4[r])[kk];
                    acc[r][0] += gv * w.x;
                    acc[r][1] += gv * w.y;
                }
            }
        }
#pragma unroll
        for (int r = 0; r < 4; ++r) {
            *(float2*)&t1[r0 + r][c2] =
                make_float2(fmaxf(acc[r][0], 0.f), fmaxf(acc[r][1], 0.f));
        }
    }

    // ---- phase 3: u = hin + relu(t1 @ w2 + b2); fused layernorm ----
    {
        float acc[4][2];
        const float2 bv = *(const float2*)(b2 + c2);
#pragma unroll
        for (int r = 0; r < 4; ++r) { acc[r][0] = bv.x; acc[r][1] = bv.y; }
        for (int k4 = 0; k4 < HID; k4 += 4) {
            float4 t4[4];
#pragma unroll
            for (int r = 0; r < 4; ++r) t4[r] = *(const float4*)&t1[r0 + r][k4];
#pragma unroll
            for (int kk = 0; kk < 4; ++kk) {
                const float2 w = *(const float2*)(w2 + (k4 + kk) * HID + c2);
#pragma unroll
                for (int r = 0; r < 4; ++r) {
                    const float tv = ((const float*)&t4[r])[kk];
                    acc[r][0] += tv * w.x;
                    acc[r][1] += tv * w.y;
                }
            }
        }
        const float2 gmv = *(const float2*)(gamma + c2);
        const float2 btv = *(const float2*)(beta + c2);
#pragma unroll
        for (int r = 0; r < 4; ++r) {
            const int n = n0 + r0 + r;
            const float2 hv = *(const float2*)(hin + (long)n * HID + c2);
            const float ux = hv.x + fmaxf(acc[r][0], 0.f);
            const float uy = hv.y + fmaxf(acc[r][1], 0.f);
            float s = ux + uy, s2 = ux * ux + uy * uy;
#pragma unroll
            for (int off = 1; off < 64; off <<= 1) {
                s += __shfl_xor(s, off);
                s2 += __shfl_xor(s2, off);
            }
            const float mu = s * (1.f / HID);
            const float var = s2 * (1.f / HID) - mu * mu;
            const float inv = rsqrtf(var + LN_EPS);
            float2 o;
            o.x = (ux - mu) * inv * gmv.x + btv.x;
            o.y = (uy - mu) * inv * gmv.y + btv.y;
            *(float2*)(hout + (long)n * HID + c2) = o;
        }
    }
}

// -------- global mean pool: segmented reduction (batch is sorted) ----
__global__ __launch_bounds__(128) void k_pool(
    const float* __restrict__ h, const int* __restrict__ batch,
    float* __restrict__ sums, float* __restrict__ cnt) {
    const int c = threadIdx.x;
    const int n0 = blockIdx.x * 128;
    if (n0 >= N_NODES) return;
    const int nend = min(n0 + 128, N_NODES);
    int cur = batch[n0];
    float acc = 0.f;
    int runlen = 0;
    for (int n = n0; n < nend; ++n) {
        const int b = batch[n];
        if (b != cur) {
            atomicAdd(&sums[(long)cur * HID + c], acc);
            if (c == 0) atomicAdd(&cnt[cur], (float)runlen);
            acc = 0.f;
            runlen = 0;
            cur = b;
        }
        acc += h[(long)n * HID + c];
        ++runlen;
    }
    atomicAdd(&sums[(long)cur * HID + c], acc);
    if (c == 0) atomicAdd(&cnt[cur], (float)runlen);
}

// ---------------- head: 1 block per graph ----------------------------
__global__ __launch_bounds__(128) void k_head(
    const float* __restrict__ sums, const float* __restrict__ cnt,
    const float* __restrict__ fcW1, const float* __restrict__ fcb1,
    const float* __restrict__ fcW2, const float* __restrict__ fcb2,
    const float* __restrict__ fcW3, const float* __restrict__ fcb3,
    float* __restrict__ out) {
    __shared__ float p[HID];
    __shared__ float o1[HID];
    __shared__ float o2[64];
    const int g = blockIdx.x, t = threadIdx.x;
    const float c = fmaxf(cnt[g], 1.0f);
    p[t] = sums[g * HID + t] / c;
    __syncthreads();
    float s = fcb1[t];
    for (int k = 0; k < HID; ++k) s += p[k] * fcW1[k * HID + t];
    o1[t] = fmaxf(s, 0.f);
    __syncthreads();
    if (t < 64) {
        float s2 = fcb2[t];
        for (int k = 0; k < HID; ++k) s2 += o1[k] * fcW2[k * 64 + t];
        o2[t] = fmaxf(s2, 0.f);
    }
    __syncthreads();
    if (t < 64) {
        float v = o2[t] * fcW3[t];
#pragma unroll
        for (int off = 32; off > 0; off >>= 1) v += __shfl_down(v, off);
        if (t == 0) out[g] = v + fcb3[0];
    }
}

extern "C" void kernel_launch(void* const* d_in, const int* in_sizes, int n_in,
                              void* d_out, int out_size, void* d_ws, size_t ws_size,
                              hipStream_t stream) {
    const float* x    = (const float*)d_in[0];
    const int*   ei   = (const int*)d_in[1];
    const float* ea   = (const float*)d_in[2];
    const int*   batch= (const int*)d_in[3];
    const float* inW  = (const float*)d_in[4];
    const float* inb  = (const float*)d_in[5];
    const float* edgeW= (const float*)d_in[6];
    const float* edgeb= (const float*)d_in[7];
    const float* w1   = (const float*)d_in[8];
    const float* b1   = (const float*)d_in[9];
    const float* w2   = (const float*)d_in[10];
    const float* b2   = (const float*)d_in[11];
    const float* gamma= (const float*)d_in[12];
    const float* beta = (const float*)d_in[13];
    const float* fcW1 = (const float*)d_in[14];
    const float* fcb1 = (const float*)d_in[15];
    const float* fcW2 = (const float*)d_in[16];
    const float* fcb2 = (const float*)d_in[17];
    const float* fcW3 = (const float*)d_in[18];
    const float* fcb3 = (const float*)d_in[19];
    float* out = (float*)d_out;

    // workspace layout (float4-aligned first)
    float4* edata  = (float4*)d_ws;                               // 1.6M float4
    float*  h0     = (float*)(edata + N_EDGES);                   // 12.8M f32
    float*  h1     = h0 + (size_t)N_NODES * HID;                  // 12.8M f32
    int*    row_ptr= (int*)(h1 + (size_t)N_NODES * HID);          // 100001
    int*    cursor = row_ptr + (N_NODES + 1);                     // 100000
    int*    deg    = cursor + N_NODES;                            // 100000
    int*    bsum   = deg + N_NODES;                               // 392
    int*    bpre   = bsum + 512;                                  // 392
    float*  sums   = (float*)(bpre + 512);                        // 1024*128
    float*  cnt    = sums + (size_t)N_GRAPHS * HID;               // 1024

    hipMemsetAsync(deg, 0, N_NODES * sizeof(int), stream);
    hipMemsetAsync(sums, 0, ((size_t)N_GRAPHS * HID + N_GRAPHS) * sizeof(float), stream);

    k_input_proj<<<(N_NODES * HID) / 256, 256, 0, stream>>>(x, inW, inb, h0);

    // CSR build (once per launch, reused across 4 layers)
    k_hist<<<N_EDGES / 256, 256, 0, stream>>>(ei, deg);
    k_scan1<<<NB_SCAN, 256, 0, stream>>>(deg, bsum);
    k_scan2<<<1, 512, 0, stream>>>(bsum, bpre);
    k_scan3<<<NB_SCAN, 256, 0, stream>>>(deg, bpre, row_ptr, cursor);
    k_scatter<<<N_EDGES / 256, 256, 0, stream>>>(ei, ea, cursor, edata);

    float* hin = h0;
    float* hout = h1;
    for (int l = 0; l < LAYERS; ++l) {
        k_node_update<<<N_NODES / 16, 256, 0, stream>>>(
            edata, row_ptr, edgeW + l * 3 * HID, edgeb + l * HID, hin, hout,
            w1 + l * HID * HID, b1 + l * HID, w2 + l * HID * HID, b2 + l * HID,
            gamma + l * HID, beta + l * HID);
        float* tmp = hin; hin = hout; hout = tmp;
    }
    // after 4 swaps, final h is back in h0 (== hin)

    k_pool<<<(N_NODES + 127) / 128, 128, 0, stream>>>(hin, batch, sums, cnt);
    k_head<<<N_GRAPHS, 128, 0, stream>>>(sums, cnt, fcW1, fcb1, fcW2, fcb2,
                                         fcW3, fcb3, out);
}

// Round 6
// 1307.129 us; speedup vs baseline: 3.1231x; 3.1231x over previous
//
#include <hip/hip_runtime.h>

#define N_NODES 100000
#define N_EDGES 1600000
#define N_GRAPHS 1024
#define HID 128
#define LAYERS 4
#define LN_EPS 1e-5f
#define LPAD (HID + 4)
#define NB_SCAN 391  // ceil(100000/256)

// ---------------- input projection: h = x @ inW + inb ----------------
__global__ __launch_bounds__(256) void k_input_proj(
    const float* __restrict__ x, const float* __restrict__ inW,
    const float* __restrict__ inb, float* __restrict__ h) {
    int idx = blockIdx.x * 256 + threadIdx.x;  // over N_NODES*HID (exact)
    int n = idx >> 7, c = idx & 127;
    const float* xr = x + n * 7;
    float s = inb[c];
#pragma unroll
    for (int k = 0; k < 7; ++k) s += xr[k] * inW[k * HID + c];
    h[idx] = s;
}

// ---------------- CSR build: histogram of dst ------------------------
__global__ __launch_bounds__(256) void k_hist(
    const int* __restrict__ ei, int* __restrict__ deg) {
    int e = blockIdx.x * 256 + threadIdx.x;  // N_EDGES exact
    atomicAdd(&deg[ei[N_EDGES + e]], 1);
}

// ---------------- CSR build: parallel 3-stage scan -------------------
__global__ __launch_bounds__(256) void k_scan1(
    const int* __restrict__ deg, int* __restrict__ bsum) {
    const int i = blockIdx.x * 256 + threadIdx.x;
    int v = (i < N_NODES) ? deg[i] : 0;
#pragma unroll
    for (int off = 1; off < 64; off <<= 1) v += __shfl_xor(v, off);
    __shared__ int wsum[4];
    if ((threadIdx.x & 63) == 0) wsum[threadIdx.x >> 6] = v;
    __syncthreads();
    if (threadIdx.x == 0) bsum[blockIdx.x] = wsum[0] + wsum[1] + wsum[2] + wsum[3];
}

__global__ __launch_bounds__(512) void k_scan2(
    const int* __restrict__ bsum, int* __restrict__ bpre) {
    __shared__ int tmp[512];
    const int t = threadIdx.x;
    int v = (t < NB_SCAN) ? bsum[t] : 0;
    tmp[t] = v;
    __syncthreads();
    for (int off = 1; off < 512; off <<= 1) {
        int u = (t >= off) ? tmp[t - off] : 0;
        __syncthreads();
        tmp[t] += u;
        __syncthreads();
    }
    if (t < NB_SCAN) bpre[t] = tmp[t] - v;  // exclusive
}

__global__ __launch_bounds__(256) void k_scan3(
    const int* __restrict__ deg, const int* __restrict__ bpre,
    int* __restrict__ row_ptr, int* __restrict__ cursor) {
    __shared__ int tmp[256];
    const int t = threadIdx.x;
    const int i = blockIdx.x * 256 + t;
    int d = (i < N_NODES) ? deg[i] : 0;
    tmp[t] = d;
    __syncthreads();
    for (int off = 1; off < 256; off <<= 1) {
        int u = (t >= off) ? tmp[t - off] : 0;
        __syncthreads();
        tmp[t] += u;
        __syncthreads();
    }
    if (i < N_NODES) {
        const int ex = bpre[blockIdx.x] + tmp[t] - d;
        row_ptr[i] = ex;
        cursor[i] = ex;
        if (i == N_NODES - 1) row_ptr[N_NODES] = N_EDGES;
    }
}

// ---------------- CSR build: scatter edges into sorted slots ---------
__global__ __launch_bounds__(256) void k_scatter(
    const int* __restrict__ ei, const float* __restrict__ ea,
    int* __restrict__ cursor, float4* __restrict__ edata) {
    int e = blockIdx.x * 256 + threadIdx.x;  // N_EDGES exact
    const int src = ei[e];
    const int dst = ei[N_EDGES + e];
    const int pos = atomicAdd(&cursor[dst], 1);
    edata[pos] = make_float4(ea[e * 3 + 0], ea[e * 3 + 1], ea[e * 3 + 2],
                             __int_as_float(src));
}

// Consume one edge's message into the right row accumulator. Plain macro
// (NO lambdas/helpers anywhere in phase 1 -- R4/R5 showed outlined helpers
// push captured state to scratch: WRITE_SIZE 50->618 MB).
#define EDGE_CONSUME(ed, g, gidx)                                              \
    {                                                                          \
        float mx = fmaxf(g.x + ed.x * ew0.x + ed.y * ew1.x + ed.z * ew2.x + ebv.x, 0.f); \
        float my = fmaxf(g.y + ed.x * ew0.y + ed.y * ew1.y + ed.z * ew2.y + ebv.y, 0.f); \
        float mz = fmaxf(g.z + ed.x * ew0.z + ed.y * ew1.z + ed.z * ew2.z + ebv.z, 0.f); \
        float mw = fmaxf(g.w + ed.x * ew0.w + ed.y * ew1.w + ed.z * ew2.w + ebv.w, 0.f); \
        if ((gidx) < rp1)      { acc0.x += mx; acc0.y += my; acc0.z += mz; acc0.w += mw; } \
        else if ((gidx) < rp2) { acc1.x += mx; acc1.y += my; acc1.z += mz; acc1.w += mw; } \
        else if ((gidx) < rp3) { acc2.x += mx; acc2.y += my; acc2.z += mz; acc2.w += mw; } \
        else                   { acc3.x += mx; acc3.y += my; acc3.z += mz; acc3.w += mw; } \
    }

// ------- fused gather-aggregate + MLP + residual + layernorm ---------
// 256 threads = 4 waves; each wave owns 4 nodes end-to-end. Phase 1 stages
// up to 64 edges at a time into a wave-private LDS tile (one coalesced
// global load per tile), then the two wave-halves (32 lanes x float4 = one
// full h-row each) gather 2 edges concurrently, 8 edges in flight.
__global__ __launch_bounds__(256) void k_node_update(
    const float4* __restrict__ edata, const int* __restrict__ row_ptr,
    const float* __restrict__ eW, const float* __restrict__ eb,
    const float* __restrict__ hin, float* __restrict__ hout,
    const float* __restrict__ w1, const float* __restrict__ b1,
    const float* __restrict__ w2, const float* __restrict__ b2,
    const float* __restrict__ gamma, const float* __restrict__ beta) {
    __shared__ float gt[16][LPAD];
    __shared__ float t1[16][LPAD];
    __shared__ float etile[4][64 * 4];  // per-wave 64-edge staging tile
    const int wave = threadIdx.x >> 6;
    const int lane = threadIdx.x & 63;
    const int n0 = blockIdx.x * 16;
    const int r0 = wave * 4;            // this wave's first row slot

    // ---- phase 1: LDS-staged gather-aggregate, 2 edges per step ----
    {
        const int half = lane >> 5;     // 0/1: which edge of the pair
        const int hl = lane & 31;
        const int c4 = hl * 4;          // this lane's 4 channels (phase 1)
        const float4 ew0 = *(const float4*)(eW + 0 * HID + c4);
        const float4 ew1 = *(const float4*)(eW + 1 * HID + c4);
        const float4 ew2 = *(const float4*)(eW + 2 * HID + c4);
        const float4 ebv = *(const float4*)(eb + c4);
        const int nb = n0 + r0;
        const int rp0 = row_ptr[nb + 0];
        const int rp1 = row_ptr[nb + 1];
        const int rp2 = row_ptr[nb + 2];
        const int rp3 = row_ptr[nb + 3];
        const int rp4 = row_ptr[nb + 4];

        float4 acc0 = {0.f, 0.f, 0.f, 0.f};
        float4 acc1 = {0.f, 0.f, 0.f, 0.f};
        float4 acc2 = {0.f, 0.f, 0.f, 0.f};
        float4 acc3 = {0.f, 0.f, 0.f, 0.f};

        for (int t = rp0; t < rp4; t += 64) {
            const int cnt = (rp4 - t < 64) ? (rp4 - t) : 64;
            // fill tile: one coalesced load per wave (same-wave LDS, no barrier)
            if (lane < cnt) {
                const float4 ed = edata[t + lane];
                *(float4*)&etile[wave][lane * 4] = ed;
            }
            int j = 0;
            for (; j + 8 <= cnt; j += 8) {
                // 4 independent LDS reads + 4 independent gathers in flight
                const float4 e0 = *(const float4*)&etile[wave][(j + 0 + half) * 4];
                const float4 e1 = *(const float4*)&etile[wave][(j + 2 + half) * 4];
                const float4 e2 = *(const float4*)&etile[wave][(j + 4 + half) * 4];
                const float4 e3 = *(const float4*)&etile[wave][(j + 6 + half) * 4];
                const float4 g0 = *(const float4*)(hin + (long)__float_as_int(e0.w) * HID + c4);
                const float4 g1 = *(const float4*)(hin + (long)__float_as_int(e1.w) * HID + c4);
                const float4 g2 = *(const float4*)(hin + (long)__float_as_int(e2.w) * HID + c4);
                const float4 g3 = *(const float4*)(hin + (long)__float_as_int(e3.w) * HID + c4);
                EDGE_CONSUME(e0, g0, t + j + 0 + half);
                EDGE_CONSUME(e1, g1, t + j + 2 + half);
                EDGE_CONSUME(e2, g2, t + j + 4 + half);
                EDGE_CONSUME(e3, g3, t + j + 6 + half);
            }
            for (; j + 2 <= cnt; j += 2) {
                const float4 e0 = *(const float4*)&etile[wave][(j + half) * 4];
                const float4 g0 = *(const float4*)(hin + (long)__float_as_int(e0.w) * HID + c4);
                EDGE_CONSUME(e0, g0, t + j + half);
            }
            if (j < cnt) {  // odd leftover edge: half 0 only
                if (half == 0) {
                    const float4 e0 = *(const float4*)&etile[wave][j * 4];
                    const float4 g0 = *(const float4*)(hin + (long)__float_as_int(e0.w) * HID + c4);
                    EDGE_CONSUME(e0, g0, t + j);
                }
            }
        }

        // combine the two halves (lane L and L+32 hold the same channels)
        acc0.x += __shfl_xor(acc0.x, 32); acc0.y += __shfl_xor(acc0.y, 32);
        acc0.z += __shfl_xor(acc0.z, 32); acc0.w += __shfl_xor(acc0.w, 32);
        acc1.x += __shfl_xor(acc1.x, 32); acc1.y += __shfl_xor(acc1.y, 32);
        acc1.z += __shfl_xor(acc1.z, 32); acc1.w += __shfl_xor(acc1.w, 32);
        acc2.x += __shfl_xor(acc2.x, 32); acc2.y += __shfl_xor(acc2.y, 32);
        acc2.z += __shfl_xor(acc2.z, 32); acc2.w += __shfl_xor(acc2.w, 32);
        acc3.x += __shfl_xor(acc3.x, 32); acc3.y += __shfl_xor(acc3.y, 32);
        acc3.z += __shfl_xor(acc3.z, 32); acc3.w += __shfl_xor(acc3.w, 32);

        if (half == 0) {
            const float4 h0v = *(const float4*)(hin + (long)(nb + 0) * HID + c4);
            const float4 h1v = *(const float4*)(hin + (long)(nb + 1) * HID + c4);
            const float4 h2v = *(const float4*)(hin + (long)(nb + 2) * HID + c4);
            const float4 h3v = *(const float4*)(hin + (long)(nb + 3) * HID + c4);
            *(float4*)&gt[r0 + 0][c4] = make_float4(h0v.x + acc0.x, h0v.y + acc0.y,
                                                    h0v.z + acc0.z, h0v.w + acc0.w);
            *(float4*)&gt[r0 + 1][c4] = make_float4(h1v.x + acc1.x, h1v.y + acc1.y,
                                                    h1v.z + acc1.z, h1v.w + acc1.w);
            *(float4*)&gt[r0 + 2][c4] = make_float4(h2v.x + acc2.x, h2v.y + acc2.y,
                                                    h2v.z + acc2.z, h2v.w + acc2.w);
            *(float4*)&gt[r0 + 3][c4] = make_float4(h3v.x + acc3.x, h3v.y + acc3.y,
                                                    h3v.z + acc3.z, h3v.w + acc3.w);
        }
    }
    // same-wave LDS producer/consumer: hardware-ordered, no barrier needed

    const int lane2 = threadIdx.x & 63;
    const int c2 = lane2 * 2;  // this thread's 2 columns for phases 2-4

    // ---- phase 2: t1 = relu(gt @ w1 + b1), b128 4-k blocking ----
    {
        float acc[4][2];
        const float2 bv = *(const float2*)(b1 + c2);
#pragma unroll
        for (int r = 0; r < 4; ++r) { acc[r][0] = bv.x; acc[r][1] = bv.y; }
        for (int k4 = 0; k4 < HID; k4 += 4) {
            float4 g4[4];
#pragma unroll
            for (int r = 0; r < 4; ++r) g4[r] = *(const float4*)&gt[r0 + r][k4];
#pragma unroll
            for (int kk = 0; kk < 4; ++kk) {
                const float2 w = *(const float2*)(w1 + (k4 + kk) * HID + c2);
#pragma unroll
                for (int r = 0; r < 4; ++r) {
                    const float gv = ((const float*)&g4[r])[kk];
                    acc[r][0] += gv * w.x;
                    acc[r][1] += gv * w.y;
                }
            }
        }
#pragma unroll
        for (int r = 0; r < 4; ++r) {
            *(float2*)&t1[r0 + r][c2] =
                make_float2(fmaxf(acc[r][0], 0.f), fmaxf(acc[r][1], 0.f));
        }
    }

    // ---- phase 3: u = hin + relu(t1 @ w2 + b2); fused layernorm ----
    {
        float acc[4][2];
        const float2 bv = *(const float2*)(b2 + c2);
#pragma unroll
        for (int r = 0; r < 4; ++r) { acc[r][0] = bv.x; acc[r][1] = bv.y; }
        for (int k4 = 0; k4 < HID; k4 += 4) {
            float4 t4[4];
#pragma unroll
            for (int r = 0; r < 4; ++r) t4[r] = *(const float4*)&t1[r0 + r][k4];
#pragma unroll
            for (int kk = 0; kk < 4; ++kk) {
                const float2 w = *(const float2*)(w2 + (k4 + kk) * HID + c2);
#pragma unroll
                for (int r = 0; r < 4; ++r) {
                    const float tv = ((const float*)&t4[r])[kk];
                    acc[r][0] += tv * w.x;
                    acc[r][1] += tv * w.y;
                }
            }
        }
        const float2 gmv = *(const float2*)(gamma + c2);
        const float2 btv = *(const float2*)(beta + c2);
#pragma unroll
        for (int r = 0; r < 4; ++r) {
            const int n = n0 + r0 + r;
            const float2 hv = *(const float2*)(hin + (long)n * HID + c2);
            const float ux = hv.x + fmaxf(acc[r][0], 0.f);
            const float uy = hv.y + fmaxf(acc[r][1], 0.f);
            float s = ux + uy, s2 = ux * ux + uy * uy;
#pragma unroll
            for (int off = 1; off < 64; off <<= 1) {
                s += __shfl_xor(s, off);
                s2 += __shfl_xor(s2, off);
            }
            const float mu = s * (1.f / HID);
            const float var = s2 * (1.f / HID) - mu * mu;
            const float inv = rsqrtf(var + LN_EPS);
            float2 o;
            o.x = (ux - mu) * inv * gmv.x + btv.x;
            o.y = (uy - mu) * inv * gmv.y + btv.y;
            *(float2*)(hout + (long)n * HID + c2) = o;
        }
    }
}

// -------- global mean pool: segmented reduction (batch is sorted) ----
__global__ __launch_bounds__(128) void k_pool(
    const float* __restrict__ h, const int* __restrict__ batch,
    float* __restrict__ sums, float* __restrict__ cnt) {
    const int c = threadIdx.x;
    const int n0 = blockIdx.x * 128;
    if (n0 >= N_NODES) return;
    const int nend = min(n0 + 128, N_NODES);
    int cur = batch[n0];
    float acc = 0.f;
    int runlen = 0;
    for (int n = n0; n < nend; ++n) {
        const int b = batch[n];
        if (b != cur) {
            atomicAdd(&sums[(long)cur * HID + c], acc);
            if (c == 0) atomicAdd(&cnt[cur], (float)runlen);
            acc = 0.f;
            runlen = 0;
            cur = b;
        }
        acc += h[(long)n * HID + c];
        ++runlen;
    }
    atomicAdd(&sums[(long)cur * HID + c], acc);
    if (c == 0) atomicAdd(&cnt[cur], (float)runlen);
}

// ---------------- head: 1 block per graph ----------------------------
__global__ __launch_bounds__(128) void k_head(
    const float* __restrict__ sums, const float* __restrict__ cnt,
    const float* __restrict__ fcW1, const float* __restrict__ fcb1,
    const float* __restrict__ fcW2, const float* __restrict__ fcb2,
    const float* __restrict__ fcW3, const float* __restrict__ fcb3,
    float* __restrict__ out) {
    __shared__ float p[HID];
    __shared__ float o1[HID];
    __shared__ float o2[64];
    const int g = blockIdx.x, t = threadIdx.x;
    const float c = fmaxf(cnt[g], 1.0f);
    p[t] = sums[g * HID + t] / c;
    __syncthreads();
    float s = fcb1[t];
    for (int k = 0; k < HID; ++k) s += p[k] * fcW1[k * HID + t];
    o1[t] = fmaxf(s, 0.f);
    __syncthreads();
    if (t < 64) {
        float s2 = fcb2[t];
        for (int k = 0; k < HID; ++k) s2 += o1[k] * fcW2[k * 64 + t];
        o2[t] = fmaxf(s2, 0.f);
    }
    __syncthreads();
    if (t < 64) {
        float v = o2[t] * fcW3[t];
#pragma unroll
        for (int off = 32; off > 0; off >>= 1) v += __shfl_down(v, off);
        if (t == 0) out[g] = v + fcb3[0];
    }
}

extern "C" void kernel_launch(void* const* d_in, const int* in_sizes, int n_in,
                              void* d_out, int out_size, void* d_ws, size_t ws_size,
                              hipStream_t stream) {
    const float* x    = (const float*)d_in[0];
    const int*   ei   = (const int*)d_in[1];
    const float* ea   = (const float*)d_in[2];
    const int*   batch= (const int*)d_in[3];
    const float* inW  = (const float*)d_in[4];
    const float* inb  = (const float*)d_in[5];
    const float* edgeW= (const float*)d_in[6];
    const float* edgeb= (const float*)d_in[7];
    const float* w1   = (const float*)d_in[8];
    const float* b1   = (const float*)d_in[9];
    const float* w2   = (const float*)d_in[10];
    const float* b2   = (const float*)d_in[11];
    const float* gamma= (const float*)d_in[12];
    const float* beta = (const float*)d_in[13];
    const float* fcW1 = (const float*)d_in[14];
    const float* fcb1 = (const float*)d_in[15];
    const float* fcW2 = (const float*)d_in[16];
    const float* fcb2 = (const float*)d_in[17];
    const float* fcW3 = (const float*)d_in[18];
    const float* fcb3 = (const float*)d_in[19];
    float* out = (float*)d_out;

    // workspace layout (float4-aligned first)
    float4* edata  = (float4*)d_ws;                               // 1.6M float4
    float*  h0     = (float*)(edata + N_EDGES);                   // 12.8M f32
    float*  h1     = h0 + (size_t)N_NODES * HID;                  // 12.8M f32
    int*    row_ptr= (int*)(h1 + (size_t)N_NODES * HID);          // 100001
    int*    cursor = row_ptr + (N_NODES + 1);                     // 100000
    int*    deg    = cursor + N_NODES;                            // 100000
    int*    bsum   = deg + N_NODES;                               // 392
    int*    bpre   = bsum + 512;                                  // 392
    float*  sums   = (float*)(bpre + 512);                        // 1024*128
    float*  cnt    = sums + (size_t)N_GRAPHS * HID;               // 1024

    hipMemsetAsync(deg, 0, N_NODES * sizeof(int), stream);
    hipMemsetAsync(sums, 0, ((size_t)N_GRAPHS * HID + N_GRAPHS) * sizeof(float), stream);

    k_input_proj<<<(N_NODES * HID) / 256, 256, 0, stream>>>(x, inW, inb, h0);

    // CSR build (once per launch, reused across 4 layers)
    k_hist<<<N_EDGES / 256, 256, 0, stream>>>(ei, deg);
    k_scan1<<<NB_SCAN, 256, 0, stream>>>(deg, bsum);
    k_scan2<<<1, 512, 0, stream>>>(bsum, bpre);
    k_scan3<<<NB_SCAN, 256, 0, stream>>>(deg, bpre, row_ptr, cursor);
    k_scatter<<<N_EDGES / 256, 256, 0, stream>>>(ei, ea, cursor, edata);

    float* hin = h0;
    float* hout = h1;
    for (int l = 0; l < LAYERS; ++l) {
        k_node_update<<<N_NODES / 16, 256, 0, stream>>>(
            edata, row_ptr, edgeW + l * 3 * HID, edgeb + l * HID, hin, hout,
            w1 + l * HID * HID, b1 + l * HID, w2 + l * HID * HID, b2 + l * HID,
            gamma + l * HID, beta + l * HID);
        float* tmp = hin; hin = hout; hout = tmp;
    }
    // after 4 swaps, final h is back in h0 (== hin)

    k_pool<<<(N_NODES + 127) / 128, 128, 0, stream>>>(hin, batch, sums, cnt);
    k_head<<<N_GRAPHS, 128, 0, stream>>>(sums, cnt, fcW1, fcb1, fcW2, fcb2,
                                         fcW3, fcb3, out);
}

// Round 7
// 1293.422 us; speedup vs baseline: 3.1562x; 1.0106x over previous
//
#include <hip/hip_runtime.h>

#define N_NODES 100000
#define N_EDGES 1600000
#define N_GRAPHS 1024
#define HID 128
#define LAYERS 4
#define LN_EPS 1e-5f
#define LPAD (HID + 4)
#define NB_SCAN 391  // ceil(100000/256)

__device__ __forceinline__ unsigned short f2bf(float x) {
    unsigned v = __float_as_uint(x);
    return (unsigned short)((v + 0x7fffu + ((v >> 16) & 1u)) >> 16);
}
#define BF4(q) make_float4(__uint_as_float(((unsigned)(q).x) << 16), \
                           __uint_as_float(((unsigned)(q).y) << 16), \
                           __uint_as_float(((unsigned)(q).z) << 16), \
                           __uint_as_float(((unsigned)(q).w) << 16))

// ---------------- input projection: h = x @ inW + inb ----------------
__global__ __launch_bounds__(256) void k_input_proj(
    const float* __restrict__ x, const float* __restrict__ inW,
    const float* __restrict__ inb, float* __restrict__ h,
    unsigned short* __restrict__ hb) {
    int idx = blockIdx.x * 256 + threadIdx.x;  // over N_NODES*HID (exact)
    int n = idx >> 7, c = idx & 127;
    const float* xr = x + n * 7;
    float s = inb[c];
#pragma unroll
    for (int k = 0; k < 7; ++k) s += xr[k] * inW[k * HID + c];
    h[idx] = s;
    hb[idx] = f2bf(s);
}

// ---------------- CSR build: histogram of dst ------------------------
__global__ __launch_bounds__(256) void k_hist(
    const int* __restrict__ ei, int* __restrict__ deg) {
    int e = blockIdx.x * 256 + threadIdx.x;  // N_EDGES exact
    atomicAdd(&deg[ei[N_EDGES + e]], 1);
}

// ---------------- CSR build: parallel 3-stage scan -------------------
__global__ __launch_bounds__(256) void k_scan1(
    const int* __restrict__ deg, int* __restrict__ bsum) {
    const int i = blockIdx.x * 256 + threadIdx.x;
    int v = (i < N_NODES) ? deg[i] : 0;
#pragma unroll
    for (int off = 1; off < 64; off <<= 1) v += __shfl_xor(v, off);
    __shared__ int wsum[4];
    if ((threadIdx.x & 63) == 0) wsum[threadIdx.x >> 6] = v;
    __syncthreads();
    if (threadIdx.x == 0) bsum[blockIdx.x] = wsum[0] + wsum[1] + wsum[2] + wsum[3];
}

__global__ __launch_bounds__(512) void k_scan2(
    const int* __restrict__ bsum, int* __restrict__ bpre) {
    __shared__ int tmp[512];
    const int t = threadIdx.x;
    int v = (t < NB_SCAN) ? bsum[t] : 0;
    tmp[t] = v;
    __syncthreads();
    for (int off = 1; off < 512; off <<= 1) {
        int u = (t >= off) ? tmp[t - off] : 0;
        __syncthreads();
        tmp[t] += u;
        __syncthreads();
    }
    if (t < NB_SCAN) bpre[t] = tmp[t] - v;  // exclusive
}

__global__ __launch_bounds__(256) void k_scan3(
    const int* __restrict__ deg, const int* __restrict__ bpre,
    int* __restrict__ row_ptr, int* __restrict__ cursor) {
    __shared__ int tmp[256];
    const int t = threadIdx.x;
    const int i = blockIdx.x * 256 + t;
    int d = (i < N_NODES) ? deg[i] : 0;
    tmp[t] = d;
    __syncthreads();
    for (int off = 1; off < 256; off <<= 1) {
        int u = (t >= off) ? tmp[t - off] : 0;
        __syncthreads();
        tmp[t] += u;
        __syncthreads();
    }
    if (i < N_NODES) {
        const int ex = bpre[blockIdx.x] + tmp[t] - d;
        row_ptr[i] = ex;
        cursor[i] = ex;
        if (i == N_NODES - 1) row_ptr[N_NODES] = N_EDGES;
    }
}

// ---------------- CSR build: scatter edges into sorted slots ---------
__global__ __launch_bounds__(256) void k_scatter(
    const int* __restrict__ ei, const float* __restrict__ ea,
    int* __restrict__ cursor, float4* __restrict__ edata) {
    int e = blockIdx.x * 256 + threadIdx.x;  // N_EDGES exact
    const int src = ei[e];
    const int dst = ei[N_EDGES + e];
    const int pos = atomicAdd(&cursor[dst], 1);
    edata[pos] = make_float4(ea[e * 3 + 0], ea[e * 3 + 1], ea[e * 3 + 2],
                             __int_as_float(src));
}

// Consume one edge's message into the right row accumulator (macro only:
// outlined helpers push captured state to scratch -- R4/R5 lesson).
#define EDGE_CONSUME(ed, g, gidx)                                              \
    {                                                                          \
        float mx = fmaxf(g.x + ed.x * ew0.x + ed.y * ew1.x + ed.z * ew2.x + ebv.x, 0.f); \
        float my = fmaxf(g.y + ed.x * ew0.y + ed.y * ew1.y + ed.z * ew2.y + ebv.y, 0.f); \
        float mz = fmaxf(g.z + ed.x * ew0.z + ed.y * ew1.z + ed.z * ew2.z + ebv.z, 0.f); \
        float mw = fmaxf(g.w + ed.x * ew0.w + ed.y * ew1.w + ed.z * ew2.w + ebv.w, 0.f); \
        if ((gidx) < rp1)      { acc0.x += mx; acc0.y += my; acc0.z += mz; acc0.w += mw; } \
        else if ((gidx) < rp2) { acc1.x += mx; acc1.y += my; acc1.z += mz; acc1.w += mw; } \
        else if ((gidx) < rp3) { acc2.x += mx; acc2.y += my; acc2.z += mz; acc2.w += mw; } \
        else                   { acc3.x += mx; acc3.y += my; acc3.z += mz; acc3.w += mw; } \
    }

#define EDGE_GATHER(eD, gD)                                                    \
    const ushort4 q_##gD = *(const ushort4*)(hbin + (long)__float_as_int(eD.w) * HID + c4); \
    const float4 gD = BF4(q_##gD);

// ------- fused gather-aggregate + MLP + residual + layernorm ---------
// 256 threads = 4 waves; each wave owns 4 nodes end-to-end. Phase 1 stages
// 64 edges into a wave-private LDS tile, then the two wave-halves gather
// neighbor rows from the bf16 shadow copy (256 B/row): 8 gathers in flight.
// fp32 h is read only for own rows -> single-buffered, updated in place.
__global__ __launch_bounds__(256) void k_node_update(
    const float4* __restrict__ edata, const int* __restrict__ row_ptr,
    const float* __restrict__ eW, const float* __restrict__ eb,
    float* __restrict__ h, const unsigned short* __restrict__ hbin,
    unsigned short* __restrict__ hbout,
    const float* __restrict__ w1, const float* __restrict__ b1,
    const float* __restrict__ w2, const float* __restrict__ b2,
    const float* __restrict__ gamma, const float* __restrict__ beta) {
    __shared__ float gt[16][LPAD];
    __shared__ float t1[16][LPAD];
    __shared__ float etile[4][64 * 4];  // per-wave 64-edge staging tile
    const int wave = threadIdx.x >> 6;
    const int lane = threadIdx.x & 63;
    const int n0 = blockIdx.x * 16;
    const int r0 = wave * 4;            // this wave's first row slot

    // ---- phase 1: LDS-staged bf16 gather-aggregate ----
    {
        const int half = lane >> 5;     // 0/1: which edge of the pair
        const int hl = lane & 31;
        const int c4 = hl * 4;          // this lane's 4 channels (phase 1)
        const float4 ew0 = *(const float4*)(eW + 0 * HID + c4);
        const float4 ew1 = *(const float4*)(eW + 1 * HID + c4);
        const float4 ew2 = *(const float4*)(eW + 2 * HID + c4);
        const float4 ebv = *(const float4*)(eb + c4);
        const int nb = n0 + r0;
        const int rp0 = row_ptr[nb + 0];
        const int rp1 = row_ptr[nb + 1];
        const int rp2 = row_ptr[nb + 2];
        const int rp3 = row_ptr[nb + 3];
        const int rp4 = row_ptr[nb + 4];

        float4 acc0 = {0.f, 0.f, 0.f, 0.f};
        float4 acc1 = {0.f, 0.f, 0.f, 0.f};
        float4 acc2 = {0.f, 0.f, 0.f, 0.f};
        float4 acc3 = {0.f, 0.f, 0.f, 0.f};

        for (int t = rp0; t < rp4; t += 64) {
            const int cnt = (rp4 - t < 64) ? (rp4 - t) : 64;
            // fill tile: one coalesced load per wave (same-wave LDS, no barrier)
            if (lane < cnt) {
                const float4 ed = edata[t + lane];
                *(float4*)&etile[wave][lane * 4] = ed;
            }
            int j = 0;
            for (; j + 16 <= cnt; j += 16) {
                const float4 e0 = *(const float4*)&etile[wave][(j + 0 + half) * 4];
                const float4 e1 = *(const float4*)&etile[wave][(j + 2 + half) * 4];
                const float4 e2 = *(const float4*)&etile[wave][(j + 4 + half) * 4];
                const float4 e3 = *(const float4*)&etile[wave][(j + 6 + half) * 4];
                const float4 e4 = *(const float4*)&etile[wave][(j + 8 + half) * 4];
                const float4 e5 = *(const float4*)&etile[wave][(j + 10 + half) * 4];
                const float4 e6 = *(const float4*)&etile[wave][(j + 12 + half) * 4];
                const float4 e7 = *(const float4*)&etile[wave][(j + 14 + half) * 4];
                EDGE_GATHER(e0, g0) EDGE_GATHER(e1, g1)
                EDGE_GATHER(e2, g2) EDGE_GATHER(e3, g3)
                EDGE_GATHER(e4, g4) EDGE_GATHER(e5, g5)
                EDGE_GATHER(e6, g6) EDGE_GATHER(e7, g7)
                EDGE_CONSUME(e0, g0, t + j + 0 + half);
                EDGE_CONSUME(e1, g1, t + j + 2 + half);
                EDGE_CONSUME(e2, g2, t + j + 4 + half);
                EDGE_CONSUME(e3, g3, t + j + 6 + half);
                EDGE_CONSUME(e4, g4, t + j + 8 + half);
                EDGE_CONSUME(e5, g5, t + j + 10 + half);
                EDGE_CONSUME(e6, g6, t + j + 12 + half);
                EDGE_CONSUME(e7, g7, t + j + 14 + half);
            }
            for (; j + 2 <= cnt; j += 2) {
                const float4 e0 = *(const float4*)&etile[wave][(j + half) * 4];
                EDGE_GATHER(e0, g0)
                EDGE_CONSUME(e0, g0, t + j + half);
            }
            if (j < cnt) {  // odd leftover edge: half 0 only
                if (half == 0) {
                    const float4 e0 = *(const float4*)&etile[wave][j * 4];
                    EDGE_GATHER(e0, g0)
                    EDGE_CONSUME(e0, g0, t + j);
                }
            }
        }

        // combine the two halves (lane L and L+32 hold the same channels)
        acc0.x += __shfl_xor(acc0.x, 32); acc0.y += __shfl_xor(acc0.y, 32);
        acc0.z += __shfl_xor(acc0.z, 32); acc0.w += __shfl_xor(acc0.w, 32);
        acc1.x += __shfl_xor(acc1.x, 32); acc1.y += __shfl_xor(acc1.y, 32);
        acc1.z += __shfl_xor(acc1.z, 32); acc1.w += __shfl_xor(acc1.w, 32);
        acc2.x += __shfl_xor(acc2.x, 32); acc2.y += __shfl_xor(acc2.y, 32);
        acc2.z += __shfl_xor(acc2.z, 32); acc2.w += __shfl_xor(acc2.w, 32);
        acc3.x += __shfl_xor(acc3.x, 32); acc3.y += __shfl_xor(acc3.y, 32);
        acc3.z += __shfl_xor(acc3.z, 32); acc3.w += __shfl_xor(acc3.w, 32);

        if (half == 0) {
            const float4 h0v = *(const float4*)(h + (long)(nb + 0) * HID + c4);
            const float4 h1v = *(const float4*)(h + (long)(nb + 1) * HID + c4);
            const float4 h2v = *(const float4*)(h + (long)(nb + 2) * HID + c4);
            const float4 h3v = *(const float4*)(h + (long)(nb + 3) * HID + c4);
            *(float4*)&gt[r0 + 0][c4] = make_float4(h0v.x + acc0.x, h0v.y + acc0.y,
                                                    h0v.z + acc0.z, h0v.w + acc0.w);
            *(float4*)&gt[r0 + 1][c4] = make_float4(h1v.x + acc1.x, h1v.y + acc1.y,
                                                    h1v.z + acc1.z, h1v.w + acc1.w);
            *(float4*)&gt[r0 + 2][c4] = make_float4(h2v.x + acc2.x, h2v.y + acc2.y,
                                                    h2v.z + acc2.z, h2v.w + acc2.w);
            *(float4*)&gt[r0 + 3][c4] = make_float4(h3v.x + acc3.x, h3v.y + acc3.y,
                                                    h3v.z + acc3.z, h3v.w + acc3.w);
        }
    }
    // same-wave LDS producer/consumer: hardware-ordered, no barrier needed

    const int lane2 = threadIdx.x & 63;
    const int c2 = lane2 * 2;  // this thread's 2 columns for phases 2-4

    // ---- phase 2: t1 = relu(gt @ w1 + b1), b128 4-k blocking ----
    {
        float acc[4][2];
        const float2 bv = *(const float2*)(b1 + c2);
#pragma unroll
        for (int r = 0; r < 4; ++r) { acc[r][0] = bv.x; acc[r][1] = bv.y; }
        for (int k4 = 0; k4 < HID; k4 += 4) {
            float4 g4[4];
#pragma unroll
            for (int r = 0; r < 4; ++r) g4[r] = *(const float4*)&gt[r0 + r][k4];
#pragma unroll
            for (int kk = 0; kk < 4; ++kk) {
                const float2 w = *(const float2*)(w1 + (k4 + kk) * HID + c2);
#pragma unroll
                for (int r = 0; r < 4; ++r) {
                    const float gv = ((const float*)&g4[r])[kk];
                    acc[r][0] += gv * w.x;
                    acc[r][1] += gv * w.y;
                }
            }
        }
#pragma unroll
        for (int r = 0; r < 4; ++r) {
            *(float2*)&t1[r0 + r][c2] =
                make_float2(fmaxf(acc[r][0], 0.f), fmaxf(acc[r][1], 0.f));
        }
    }

    // ---- phase 3: u = h + relu(t1 @ w2 + b2); fused layernorm ----
    {
        float acc[4][2];
        const float2 bv = *(const float2*)(b2 + c2);
#pragma unroll
        for (int r = 0; r < 4; ++r) { acc[r][0] = bv.x; acc[r][1] = bv.y; }
        for (int k4 = 0; k4 < HID; k4 += 4) {
            float4 t4[4];
#pragma unroll
            for (int r = 0; r < 4; ++r) t4[r] = *(const float4*)&t1[r0 + r][k4];
#pragma unroll
            for (int kk = 0; kk < 4; ++kk) {
                const float2 w = *(const float2*)(w2 + (k4 + kk) * HID + c2);
#pragma unroll
                for (int r = 0; r < 4; ++r) {
                    const float tv = ((const float*)&t4[r])[kk];
                    acc[r][0] += tv * w.x;
                    acc[r][1] += tv * w.y;
                }
            }
        }
        const float2 gmv = *(const float2*)(gamma + c2);
        const float2 btv = *(const float2*)(beta + c2);
#pragma unroll
        for (int r = 0; r < 4; ++r) {
            const int n = n0 + r0 + r;
            const float2 hv = *(const float2*)(h + (long)n * HID + c2);
            const float ux = hv.x + fmaxf(acc[r][0], 0.f);
            const float uy = hv.y + fmaxf(acc[r][1], 0.f);
            float s = ux + uy, s2 = ux * ux + uy * uy;
#pragma unroll
            for (int off = 1; off < 64; off <<= 1) {
                s += __shfl_xor(s, off);
                s2 += __shfl_xor(s2, off);
            }
            const float mu = s * (1.f / HID);
            const float var = s2 * (1.f / HID) - mu * mu;
            const float inv = rsqrtf(var + LN_EPS);
            float2 o;
            o.x = (ux - mu) * inv * gmv.x + btv.x;
            o.y = (uy - mu) * inv * gmv.y + btv.y;
            *(float2*)(h + (long)n * HID + c2) = o;  // in-place (own row)
            ((unsigned*)hbout)[(long)n * (HID / 2) + lane2] =
                (unsigned)f2bf(o.x) | ((unsigned)f2bf(o.y) << 16);
        }
    }
}

// -------- global mean pool: segmented reduction (batch is sorted) ----
__global__ __launch_bounds__(128) void k_pool(
    const float* __restrict__ h, const int* __restrict__ batch,
    float* __restrict__ sums, float* __restrict__ cnt) {
    const int c = threadIdx.x;
    const int n0 = blockIdx.x * 128;
    if (n0 >= N_NODES) return;
    const int nend = min(n0 + 128, N_NODES);
    int cur = batch[n0];
    float acc = 0.f;
    int runlen = 0;
    for (int n = n0; n < nend; ++n) {
        const int b = batch[n];
        if (b != cur) {
            atomicAdd(&sums[(long)cur * HID + c], acc);
            if (c == 0) atomicAdd(&cnt[cur], (float)runlen);
            acc = 0.f;
            runlen = 0;
            cur = b;
        }
        acc += h[(long)n * HID + c];
        ++runlen;
    }
    atomicAdd(&sums[(long)cur * HID + c], acc);
    if (c == 0) atomicAdd(&cnt[cur], (float)runlen);
}

// ---------------- head: 1 block per graph ----------------------------
__global__ __launch_bounds__(128) void k_head(
    const float* __restrict__ sums, const float* __restrict__ cnt,
    const float* __restrict__ fcW1, const float* __restrict__ fcb1,
    const float* __restrict__ fcW2, const float* __restrict__ fcb2,
    const float* __restrict__ fcW3, const float* __restrict__ fcb3,
    float* __restrict__ out) {
    __shared__ float p[HID];
    __shared__ float o1[HID];
    __shared__ float o2[64];
    const int g = blockIdx.x, t = threadIdx.x;
    const float c = fmaxf(cnt[g], 1.0f);
    p[t] = sums[g * HID + t] / c;
    __syncthreads();
    float s = fcb1[t];
    for (int k = 0; k < HID; ++k) s += p[k] * fcW1[k * HID + t];
    o1[t] = fmaxf(s, 0.f);
    __syncthreads();
    if (t < 64) {
        float s2 = fcb2[t];
        for (int k = 0; k < HID; ++k) s2 += o1[k] * fcW2[k * 64 + t];
        o2[t] = fmaxf(s2, 0.f);
    }
    __syncthreads();
    if (t < 64) {
        float v = o2[t] * fcW3[t];
#pragma unroll
        for (int off = 32; off > 0; off >>= 1) v += __shfl_down(v, off);
        if (t == 0) out[g] = v + fcb3[0];
    }
}

extern "C" void kernel_launch(void* const* d_in, const int* in_sizes, int n_in,
                              void* d_out, int out_size, void* d_ws, size_t ws_size,
                              hipStream_t stream) {
    const float* x    = (const float*)d_in[0];
    const int*   ei   = (const int*)d_in[1];
    const float* ea   = (const float*)d_in[2];
    const int*   batch= (const int*)d_in[3];
    const float* inW  = (const float*)d_in[4];
    const float* inb  = (const float*)d_in[5];
    const float* edgeW= (const float*)d_in[6];
    const float* edgeb= (const float*)d_in[7];
    const float* w1   = (const float*)d_in[8];
    const float* b1   = (const float*)d_in[9];
    const float* w2   = (const float*)d_in[10];
    const float* b2   = (const float*)d_in[11];
    const float* gamma= (const float*)d_in[12];
    const float* beta = (const float*)d_in[13];
    const float* fcW1 = (const float*)d_in[14];
    const float* fcb1 = (const float*)d_in[15];
    const float* fcW2 = (const float*)d_in[16];
    const float* fcb2 = (const float*)d_in[17];
    const float* fcW3 = (const float*)d_in[18];
    const float* fcb3 = (const float*)d_in[19];
    float* out = (float*)d_out;

    // workspace layout (float4-aligned first): ~128.5 MB total
    float4* edata  = (float4*)d_ws;                               // 25.6 MB
    float*  h      = (float*)(edata + N_EDGES);                   // 51.2 MB (single, in-place)
    unsigned short* hb0 = (unsigned short*)(h + (size_t)N_NODES * HID);  // 25.6 MB
    unsigned short* hb1 = hb0 + (size_t)N_NODES * HID;            // 25.6 MB
    int*    row_ptr= (int*)(hb1 + (size_t)N_NODES * HID);         // 100001
    int*    cursor = row_ptr + (N_NODES + 1);                     // 100000
    int*    deg    = cursor + N_NODES;                            // 100000
    int*    bsum   = deg + N_NODES;                               // 392
    int*    bpre   = bsum + 512;                                  // 392
    float*  sums   = (float*)(bpre + 512);                        // 1024*128
    float*  cnt    = sums + (size_t)N_GRAPHS * HID;               // 1024

    hipMemsetAsync(deg, 0, N_NODES * sizeof(int), stream);
    hipMemsetAsync(sums, 0, ((size_t)N_GRAPHS * HID + N_GRAPHS) * sizeof(float), stream);

    k_input_proj<<<(N_NODES * HID) / 256, 256, 0, stream>>>(x, inW, inb, h, hb0);

    // CSR build (once per launch, reused across 4 layers)
    k_hist<<<N_EDGES / 256, 256, 0, stream>>>(ei, deg);
    k_scan1<<<NB_SCAN, 256, 0, stream>>>(deg, bsum);
    k_scan2<<<1, 512, 0, stream>>>(bsum, bpre);
    k_scan3<<<NB_SCAN, 256, 0, stream>>>(deg, bpre, row_ptr, cursor);
    k_scatter<<<N_EDGES / 256, 256, 0, stream>>>(ei, ea, cursor, edata);

    unsigned short* hbin = hb0;
    unsigned short* hbout = hb1;
    for (int l = 0; l < LAYERS; ++l) {
        k_node_update<<<N_NODES / 16, 256, 0, stream>>>(
            edata, row_ptr, edgeW + l * 3 * HID, edgeb + l * HID,
            h, hbin, hbout,
            w1 + l * HID * HID, b1 + l * HID, w2 + l * HID * HID, b2 + l * HID,
            gamma + l * HID, beta + l * HID);
        unsigned short* tmp = hbin; hbin = hbout; hbout = tmp;
    }
    // final h is in-place in `h` (fp32)

    k_pool<<<(N_NODES + 127) / 128, 128, 0, stream>>>(h, batch, sums, cnt);
    k_head<<<N_GRAPHS, 128, 0, stream>>>(sums, cnt, fcW1, fcb1, fcW2, fcb2,
                                         fcW3, fcb3, out);
}

// Round 8
// 836.061 us; speedup vs baseline: 4.8827x; 1.5470x over previous
//
#include <hip/hip_runtime.h>

#define N_NODES 100000
#define N_EDGES 1600000
#define N_GRAPHS 1024
#define HID 128
#define LAYERS 4
#define LN_EPS 1e-5f
#define NB_SCAN 391  // ceil(100000/256)
#define GTS 136      // ushort row stride for bf16 LDS planes (16B-aligned)
#define UBS 132      // float row stride for u_buf

typedef __attribute__((ext_vector_type(8))) short bf16x8;
typedef __attribute__((ext_vector_type(4))) float f32x4;

__device__ __forceinline__ unsigned short f2bf(float x) {
    unsigned v = __float_as_uint(x);
    return (unsigned short)((v + 0x7fffu + ((v >> 16) & 1u)) >> 16);
}
__device__ __forceinline__ float bfval(unsigned short u) {
    return __uint_as_float((unsigned)u << 16);
}

// ---------------- input projection: h = x @ inW + inb ----------------
__global__ __launch_bounds__(256) void k_input_proj(
    const float* __restrict__ x, const float* __restrict__ inW,
    const float* __restrict__ inb, float* __restrict__ h,
    unsigned short* __restrict__ hb) {
    int idx = blockIdx.x * 256 + threadIdx.x;  // over N_NODES*HID (exact)
    int n = idx >> 7, c = idx & 127;
    const float* xr = x + n * 7;
    float s = inb[c];
#pragma unroll
    for (int k = 0; k < 7; ++k) s += xr[k] * inW[k * HID + c];
    h[idx] = s;
    hb[idx] = f2bf(s);
}

// ------- weight pre-swizzle into MFMA fragment order, hi/lo bf16 -----
// dst[idx] with idx = ((wid*8 + nt)*4 + ks)*64*8 + lane*8 + j  (== idx)
// src = W[(ks*32 + (lane>>4)*8 + j)*128 + nt*16 + (lane&15)]
__global__ __launch_bounds__(256) void k_wconv(
    const float* __restrict__ w1, const float* __restrict__ w2,
    unsigned short* __restrict__ wf_hi, unsigned short* __restrict__ wf_lo) {
    int idx = blockIdx.x * 256 + threadIdx.x;  // LAYERS*2*16384 exact
    int wid = idx >> 14;
    int layer = wid >> 1, which = wid & 1;
    int within = idx & 16383;
    int nt = within >> 11;
    int ks = (within >> 9) & 3;
    int ln = (within >> 3) & 63;
    int j = within & 7;
    const float* W = (which ? w2 : w1) + layer * HID * HID;
    int k = ks * 32 + (ln >> 4) * 8 + j;
    int n = nt * 16 + (ln & 15);
    float v = W[k * HID + n];
    unsigned short hi = f2bf(v);
    wf_hi[idx] = hi;
    wf_lo[idx] = f2bf(v - bfval(hi));
}

// ---------------- CSR build: histogram of dst ------------------------
__global__ __launch_bounds__(256) void k_hist(
    const int* __restrict__ ei, int* __restrict__ deg) {
    int e = blockIdx.x * 256 + threadIdx.x;  // N_EDGES exact
    atomicAdd(&deg[ei[N_EDGES + e]], 1);
}

// ---------------- CSR build: parallel 3-stage scan -------------------
__global__ __launch_bounds__(256) void k_scan1(
    const int* __restrict__ deg, int* __restrict__ bsum) {
    const int i = blockIdx.x * 256 + threadIdx.x;
    int v = (i < N_NODES) ? deg[i] : 0;
#pragma unroll
    for (int off = 1; off < 64; off <<= 1) v += __shfl_xor(v, off);
    __shared__ int wsum[4];
    if ((threadIdx.x & 63) == 0) wsum[threadIdx.x >> 6] = v;
    __syncthreads();
    if (threadIdx.x == 0) bsum[blockIdx.x] = wsum[0] + wsum[1] + wsum[2] + wsum[3];
}

__global__ __launch_bounds__(512) void k_scan2(
    const int* __restrict__ bsum, int* __restrict__ bpre) {
    __shared__ int tmp[512];
    const int t = threadIdx.x;
    int v = (t < NB_SCAN) ? bsum[t] : 0;
    tmp[t] = v;
    __syncthreads();
    for (int off = 1; off < 512; off <<= 1) {
        int u = (t >= off) ? tmp[t - off] : 0;
        __syncthreads();
        tmp[t] += u;
        __syncthreads();
    }
    if (t < NB_SCAN) bpre[t] = tmp[t] - v;  // exclusive
}

__global__ __launch_bounds__(256) void k_scan3(
    const int* __restrict__ deg, const int* __restrict__ bpre,
    int* __restrict__ row_ptr, int* __restrict__ cursor) {
    __shared__ int tmp[256];
    const int t = threadIdx.x;
    const int i = blockIdx.x * 256 + t;
    int d = (i < N_NODES) ? deg[i] : 0;
    tmp[t] = d;
    __syncthreads();
    for (int off = 1; off < 256; off <<= 1) {
        int u = (t >= off) ? tmp[t - off] : 0;
        __syncthreads();
        tmp[t] += u;
        __syncthreads();
    }
    if (i < N_NODES) {
        const int ex = bpre[blockIdx.x] + tmp[t] - d;
        row_ptr[i] = ex;
        cursor[i] = ex;
        if (i == N_NODES - 1) row_ptr[N_NODES] = N_EDGES;
    }
}

// ---------------- CSR build: scatter edges into sorted slots ---------
__global__ __launch_bounds__(256) void k_scatter(
    const int* __restrict__ ei, const float* __restrict__ ea,
    int* __restrict__ cursor, float4* __restrict__ edata) {
    int e = blockIdx.x * 256 + threadIdx.x;  // N_EDGES exact
    const int src = ei[e];
    const int dst = ei[N_EDGES + e];
    const int pos = atomicAdd(&cursor[dst], 1);
    edata[pos] = make_float4(ea[e * 3 + 0], ea[e * 3 + 1], ea[e * 3 + 2],
                             __int_as_float(src));
}

// -- phase-1 edge macros (macros only: outlined helpers spill, R4/R5) --
#define E_LOAD(JJ)                                                             \
    const float4 ed##JJ = *(const float4*)&etile[wbase + (j + JJ) * 4];        \
    const unsigned gq##JJ = *(const unsigned*)(hbin +                          \
        (long)__builtin_amdgcn_readfirstlane(__float_as_int(ed##JJ.w)) * HID + c2);

#define E_CONS(JJ) {                                                           \
    const float gx = __uint_as_float(gq##JJ << 16);                            \
    const float gy = __uint_as_float(gq##JJ & 0xffff0000u);                    \
    const float mx = fmaxf(fmaf(ed##JJ.z, ew2.x, fmaf(ed##JJ.y, ew1.x,         \
                     fmaf(ed##JJ.x, ew0.x, gx + ebv.x))), 0.f);                \
    const float my = fmaxf(fmaf(ed##JJ.z, ew2.y, fmaf(ed##JJ.y, ew1.y,         \
                     fmaf(ed##JJ.x, ew0.y, gy + ebv.y))), 0.f);                \
    const int gi = t + j + (JJ);                                               \
    if (gi < rp1)      { a0x += mx; a0y += my; }                               \
    else if (gi < rp2) { a1x += mx; a1y += my; }                               \
    else if (gi < rp3) { a2x += mx; a2y += my; }                               \
    else               { a3x += mx; a3y += my; } }

#define ROW_OUT(R, AX, AY) {                                                   \
    const float2 hv = *(const float2*)(h + (long)(nb + (R)) * HID + c2);       \
    const float gx = hv.x + (AX), gy = hv.y + (AY);                            \
    const unsigned short hx = f2bf(gx), hy = f2bf(gy);                         \
    const unsigned short lx = f2bf(gx - bfval(hx)), ly = f2bf(gy - bfval(hy)); \
    *(unsigned*)&gt_hi[(r0 + (R)) * GTS + c2] = (unsigned)hx | ((unsigned)hy << 16); \
    *(unsigned*)&gt_lo[(r0 + (R)) * GTS + c2] = (unsigned)lx | ((unsigned)ly << 16); }

#define T1_OUT(CC, NT) {                                                       \
    const float4 bv = *(const float4*)(b1 + (NT) * 16 + q4);                   \
    const float v0 = fmaxf(CC[0] + bv.x, 0.f);                                 \
    const float v1 = fmaxf(CC[1] + bv.y, 0.f);                                 \
    const float v2 = fmaxf(CC[2] + bv.z, 0.f);                                 \
    const float v3 = fmaxf(CC[3] + bv.w, 0.f);                                 \
    const unsigned short h0_ = f2bf(v0), h1_ = f2bf(v1), h2_ = f2bf(v2), h3_ = f2bf(v3); \
    const unsigned short l0_ = f2bf(v0 - bfval(h0_)), l1_ = f2bf(v1 - bfval(h1_)); \
    const unsigned short l2_ = f2bf(v2 - bfval(h2_)), l3_ = f2bf(v3 - bfval(h3_)); \
    *(uint2*)&t1_hi[ln15 * GTS + (NT) * 16 + q4] =                             \
        make_uint2((unsigned)h0_ | ((unsigned)h1_ << 16), (unsigned)h2_ | ((unsigned)h3_ << 16)); \
    *(uint2*)&t1_lo[ln15 * GTS + (NT) * 16 + q4] =                             \
        make_uint2((unsigned)l0_ | ((unsigned)l1_ << 16), (unsigned)l2_ | ((unsigned)l3_ << 16)); }

#define U_OUT(CC, NT) {                                                        \
    const float4 bv = *(const float4*)(b2 + (NT) * 16 + q4);                   \
    const float4 hv = *(const float4*)(h + (long)(n0 + ln15) * HID + (NT) * 16 + q4); \
    float4 u;                                                                  \
    u.x = hv.x + fmaxf(CC[0] + bv.x, 0.f);                                     \
    u.y = hv.y + fmaxf(CC[1] + bv.y, 0.f);                                     \
    u.z = hv.z + fmaxf(CC[2] + bv.z, 0.f);                                     \
    u.w = hv.w + fmaxf(CC[3] + bv.w, 0.f);                                     \
    *(float4*)&u_buf[ln15 * UBS + (NT) * 16 + q4] = u; }

// ------- fused gather-aggregate + MFMA MLP + residual + layernorm ----
// 256 threads = 4 waves, 16 nodes/block. Phase 1: full wave per edge
// (scalar row select), bf16 gathers. GEMMs: mfma_f32_16x16x32_bf16 with
// hi/lo split on BOTH operands (3-MFMA compensated product) so GEMM
// rounding is negligible vs the 1.5e-3 threshold.
__global__ __launch_bounds__(256) void k_node_update(
    const float4* __restrict__ edata, const int* __restrict__ row_ptr,
    const float* __restrict__ eW, const float* __restrict__ eb,
    float* __restrict__ h, const unsigned short* __restrict__ hbin,
    unsigned short* __restrict__ hbout,
    const unsigned short* __restrict__ w1f_hi, const unsigned short* __restrict__ w1f_lo,
    const unsigned short* __restrict__ w2f_hi, const unsigned short* __restrict__ w2f_lo,
    const float* __restrict__ b1, const float* __restrict__ b2,
    const float* __restrict__ gamma, const float* __restrict__ beta) {
    __shared__ __align__(16) unsigned char smem[25856];
    float* etile = (float*)smem;                       // [4][64*4], dead after ph1
    float* u_buf = (float*)smem;                       // [16][UBS], aliases etile
    unsigned short* gt_hi = (unsigned short*)(smem + 8448);   // [16][GTS]
    unsigned short* gt_lo = (unsigned short*)(smem + 12800);
    unsigned short* t1_hi = (unsigned short*)(smem + 17152);
    unsigned short* t1_lo = (unsigned short*)(smem + 21504);

    const int wave = threadIdx.x >> 6;
    const int lane = threadIdx.x & 63;
    const int n0 = blockIdx.x * 16;
    const int r0 = wave * 4;
    const int c2 = lane * 2;
    const int wbase = wave * 256;

    // ---- phase 1: gather-aggregate, full wave per edge ----
    {
        const float2 ew0 = *(const float2*)(eW + 0 * HID + c2);
        const float2 ew1 = *(const float2*)(eW + 1 * HID + c2);
        const float2 ew2 = *(const float2*)(eW + 2 * HID + c2);
        const float2 ebv = *(const float2*)(eb + c2);
        const int nb = n0 + r0;
        const int rp0 = __builtin_amdgcn_readfirstlane(row_ptr[nb + 0]);
        const int rp1 = __builtin_amdgcn_readfirstlane(row_ptr[nb + 1]);
        const int rp2 = __builtin_amdgcn_readfirstlane(row_ptr[nb + 2]);
        const int rp3 = __builtin_amdgcn_readfirstlane(row_ptr[nb + 3]);
        const int rp4 = __builtin_amdgcn_readfirstlane(row_ptr[nb + 4]);

        float a0x = 0.f, a0y = 0.f, a1x = 0.f, a1y = 0.f;
        float a2x = 0.f, a2y = 0.f, a3x = 0.f, a3y = 0.f;

        for (int t = rp0; t < rp4; t += 64) {
            const int cnt = (rp4 - t < 64) ? (rp4 - t) : 64;
            if (lane < cnt)
                *(float4*)&etile[wbase + lane * 4] = edata[t + lane];
            // same-wave LDS produce/consume: hardware-ordered, no barrier
            int j = 0;
            for (; j + 8 <= cnt; j += 8) {
                E_LOAD(0) E_LOAD(1) E_LOAD(2) E_LOAD(3)
                E_LOAD(4) E_LOAD(5) E_LOAD(6) E_LOAD(7)
                E_CONS(0) E_CONS(1) E_CONS(2) E_CONS(3)
                E_CONS(4) E_CONS(5) E_CONS(6) E_CONS(7)
            }
            for (; j < cnt; ++j) {
                E_LOAD(0)
                E_CONS(0)
            }
        }
        ROW_OUT(0, a0x, a0y)
        ROW_OUT(1, a1x, a1y)
        ROW_OUT(2, a2x, a2y)
        ROW_OUT(3, a3x, a3y)
    }
    __syncthreads();

    const int ln15 = lane & 15;
    const int q8 = (lane >> 4) * 8;
    const int q4 = (lane >> 4) * 4;
    const int nt0 = wave * 2, nt1 = nt0 + 1;

    // ---- phase 2: t1 = relu(gt @ w1 + b1) via MFMA (D[hid][node]) ----
    {
        f32x4 c0 = {0.f, 0.f, 0.f, 0.f};
        f32x4 c1 = {0.f, 0.f, 0.f, 0.f};
#pragma unroll
        for (int ks = 0; ks < 4; ++ks) {
            const bf16x8 bh = *(const bf16x8*)&gt_hi[ln15 * GTS + ks * 32 + q8];
            const bf16x8 bl = *(const bf16x8*)&gt_lo[ln15 * GTS + ks * 32 + q8];
            const bf16x8 a0h = *(const bf16x8*)(w1f_hi + (((nt0 * 4 + ks) * 64 + lane) << 3));
            const bf16x8 a0l = *(const bf16x8*)(w1f_lo + (((nt0 * 4 + ks) * 64 + lane) << 3));
            const bf16x8 a1h = *(const bf16x8*)(w1f_hi + (((nt1 * 4 + ks) * 64 + lane) << 3));
            const bf16x8 a1l = *(const bf16x8*)(w1f_lo + (((nt1 * 4 + ks) * 64 + lane) << 3));
            c0 = __builtin_amdgcn_mfma_f32_16x16x32_bf16(a0h, bh, c0, 0, 0, 0);
            c0 = __builtin_amdgcn_mfma_f32_16x16x32_bf16(a0h, bl, c0, 0, 0, 0);
            c0 = __builtin_amdgcn_mfma_f32_16x16x32_bf16(a0l, bh, c0, 0, 0, 0);
            c1 = __builtin_amdgcn_mfma_f32_16x16x32_bf16(a1h, bh, c1, 0, 0, 0);
            c1 = __builtin_amdgcn_mfma_f32_16x16x32_bf16(a1h, bl, c1, 0, 0, 0);
            c1 = __builtin_amdgcn_mfma_f32_16x16x32_bf16(a1l, bh, c1, 0, 0, 0);
        }
        T1_OUT(c0, nt0)
        T1_OUT(c1, nt1)
    }
    __syncthreads();

    // ---- phase 3: u = h + relu(t1 @ w2 + b2) via MFMA ----
    {
        f32x4 c0 = {0.f, 0.f, 0.f, 0.f};
        f32x4 c1 = {0.f, 0.f, 0.f, 0.f};
#pragma unroll
        for (int ks = 0; ks < 4; ++ks) {
            const bf16x8 bh = *(const bf16x8*)&t1_hi[ln15 * GTS + ks * 32 + q8];
            const bf16x8 bl = *(const bf16x8*)&t1_lo[ln15 * GTS + ks * 32 + q8];
            const bf16x8 a0h = *(const bf16x8*)(w2f_hi + (((nt0 * 4 + ks) * 64 + lane) << 3));
            const bf16x8 a0l = *(const bf16x8*)(w2f_lo + (((nt0 * 4 + ks) * 64 + lane) << 3));
            const bf16x8 a1h = *(const bf16x8*)(w2f_hi + (((nt1 * 4 + ks) * 64 + lane) << 3));
            const bf16x8 a1l = *(const bf16x8*)(w2f_lo + (((nt1 * 4 + ks) * 64 + lane) << 3));
            c0 = __builtin_amdgcn_mfma_f32_16x16x32_bf16(a0h, bh, c0, 0, 0, 0);
            c0 = __builtin_amdgcn_mfma_f32_16x16x32_bf16(a0h, bl, c0, 0, 0, 0);
            c0 = __builtin_amdgcn_mfma_f32_16x16x32_bf16(a0l, bh, c0, 0, 0, 0);
            c1 = __builtin_amdgcn_mfma_f32_16x16x32_bf16(a1h, bh, c1, 0, 0, 0);
            c1 = __builtin_amdgcn_mfma_f32_16x16x32_bf16(a1h, bl, c1, 0, 0, 0);
            c1 = __builtin_amdgcn_mfma_f32_16x16x32_bf16(a1l, bh, c1, 0, 0, 0);
        }
        U_OUT(c0, nt0)
        U_OUT(c1, nt1)
    }
    __syncthreads();

    // ---- phase 4: layernorm (wave owns rows r0..r0+3), write h + hb ----
    {
        const float2 gmv = *(const float2*)(gamma + c2);
        const float2 btv = *(const float2*)(beta + c2);
#pragma unroll
        for (int r = 0; r < 4; ++r) {
            const int row = r0 + r;
            const int n = n0 + row;
            const float2 uv = *(const float2*)&u_buf[row * UBS + c2];
            float s = uv.x + uv.y, s2 = uv.x * uv.x + uv.y * uv.y;
#pragma unroll
            for (int off = 1; off < 64; off <<= 1) {
                s += __shfl_xor(s, off);
                s2 += __shfl_xor(s2, off);
            }
            const float mu = s * (1.f / HID);
            const float var = s2 * (1.f / HID) - mu * mu;
            const float inv = rsqrtf(var + LN_EPS);
            float2 o;
            o.x = (uv.x - mu) * inv * gmv.x + btv.x;
            o.y = (uv.y - mu) * inv * gmv.y + btv.y;
            *(float2*)(h + (long)n * HID + c2) = o;
            ((unsigned*)hbout)[(long)n * (HID / 2) + lane] =
                (unsigned)f2bf(o.x) | ((unsigned)f2bf(o.y) << 16);
        }
    }
}

// -------- global mean pool: segmented reduction (batch is sorted) ----
__global__ __launch_bounds__(128) void k_pool(
    const float* __restrict__ h, const int* __restrict__ batch,
    float* __restrict__ sums, float* __restrict__ cnt) {
    const int c = threadIdx.x;
    const int n0 = blockIdx.x * 128;
    if (n0 >= N_NODES) return;
    const int nend = min(n0 + 128, N_NODES);
    int cur = batch[n0];
    float acc = 0.f;
    int runlen = 0;
    for (int n = n0; n < nend; ++n) {
        const int b = batch[n];
        if (b != cur) {
            atomicAdd(&sums[(long)cur * HID + c], acc);
            if (c == 0) atomicAdd(&cnt[cur], (float)runlen);
            acc = 0.f;
            runlen = 0;
            cur = b;
        }
        acc += h[(long)n * HID + c];
        ++runlen;
    }
    atomicAdd(&sums[(long)cur * HID + c], acc);
    if (c == 0) atomicAdd(&cnt[cur], (float)runlen);
}

// ---------------- head: 1 block per graph ----------------------------
__global__ __launch_bounds__(128) void k_head(
    const float* __restrict__ sums, const float* __restrict__ cnt,
    const float* __restrict__ fcW1, const float* __restrict__ fcb1,
    const float* __restrict__ fcW2, const float* __restrict__ fcb2,
    const float* __restrict__ fcW3, const float* __restrict__ fcb3,
    float* __restrict__ out) {
    __shared__ float p[HID];
    __shared__ float o1[HID];
    __shared__ float o2[64];
    const int g = blockIdx.x, t = threadIdx.x;
    const float c = fmaxf(cnt[g], 1.0f);
    p[t] = sums[g * HID + t] / c;
    __syncthreads();
    float s = fcb1[t];
    for (int k = 0; k < HID; ++k) s += p[k] * fcW1[k * HID + t];
    o1[t] = fmaxf(s, 0.f);
    __syncthreads();
    if (t < 64) {
        float s2 = fcb2[t];
        for (int k = 0; k < HID; ++k) s2 += o1[k] * fcW2[k * 64 + t];
        o2[t] = fmaxf(s2, 0.f);
    }
    __syncthreads();
    if (t < 64) {
        float v = o2[t] * fcW3[t];
#pragma unroll
        for (int off = 32; off > 0; off >>= 1) v += __shfl_down(v, off);
        if (t == 0) out[g] = v + fcb3[0];
    }
}

extern "C" void kernel_launch(void* const* d_in, const int* in_sizes, int n_in,
                              void* d_out, int out_size, void* d_ws, size_t ws_size,
                              hipStream_t stream) {
    const float* x    = (const float*)d_in[0];
    const int*   ei   = (const int*)d_in[1];
    const float* ea   = (const float*)d_in[2];
    const int*   batch= (const int*)d_in[3];
    const float* inW  = (const float*)d_in[4];
    const float* inb  = (const float*)d_in[5];
    const float* edgeW= (const float*)d_in[6];
    const float* edgeb= (const float*)d_in[7];
    const float* w1   = (const float*)d_in[8];
    const float* b1   = (const float*)d_in[9];
    const float* w2   = (const float*)d_in[10];
    const float* b2   = (const float*)d_in[11];
    const float* gamma= (const float*)d_in[12];
    const float* beta = (const float*)d_in[13];
    const float* fcW1 = (const float*)d_in[14];
    const float* fcb1 = (const float*)d_in[15];
    const float* fcW2 = (const float*)d_in[16];
    const float* fcb2 = (const float*)d_in[17];
    const float* fcW3 = (const float*)d_in[18];
    const float* fcb3 = (const float*)d_in[19];
    float* out = (float*)d_out;

    // workspace layout (16B-aligned blocks first): ~129 MB
    float4* edata = (float4*)d_ws;                                     // 25.6 MB
    float*  h     = (float*)(edata + N_EDGES);                         // 51.2 MB
    unsigned short* hb0 = (unsigned short*)(h + (size_t)N_NODES * HID);// 25.6 MB
    unsigned short* hb1 = hb0 + (size_t)N_NODES * HID;                 // 25.6 MB
    unsigned short* wf_hi = hb1 + (size_t)N_NODES * HID;               // 256 KB
    unsigned short* wf_lo = wf_hi + LAYERS * 2 * 16384;                // 256 KB
    int*    row_ptr = (int*)(wf_lo + LAYERS * 2 * 16384);              // 100001
    int*    cursor  = row_ptr + (N_NODES + 1);
    int*    deg     = cursor + N_NODES;
    int*    bsum    = deg + N_NODES;
    int*    bpre    = bsum + 512;
    float*  sums    = (float*)(bpre + 512);
    float*  cnt     = sums + (size_t)N_GRAPHS * HID;

    hipMemsetAsync(deg, 0, N_NODES * sizeof(int), stream);
    hipMemsetAsync(sums, 0, ((size_t)N_GRAPHS * HID + N_GRAPHS) * sizeof(float), stream);

    k_input_proj<<<(N_NODES * HID) / 256, 256, 0, stream>>>(x, inW, inb, h, hb0);
    k_wconv<<<(LAYERS * 2 * 16384) / 256, 256, 0, stream>>>(w1, w2, wf_hi, wf_lo);

    // CSR build (once per launch, reused across 4 layers)
    k_hist<<<N_EDGES / 256, 256, 0, stream>>>(ei, deg);
    k_scan1<<<NB_SCAN, 256, 0, stream>>>(deg, bsum);
    k_scan2<<<1, 512, 0, stream>>>(bsum, bpre);
    k_scan3<<<NB_SCAN, 256, 0, stream>>>(deg, bpre, row_ptr, cursor);
    k_scatter<<<N_EDGES / 256, 256, 0, stream>>>(ei, ea, cursor, edata);

    unsigned short* hbin = hb0;
    unsigned short* hbout = hb1;
    for (int l = 0; l < LAYERS; ++l) {
        k_node_update<<<N_NODES / 16, 256, 0, stream>>>(
            edata, row_ptr, edgeW + l * 3 * HID, edgeb + l * HID,
            h, hbin, hbout,
            wf_hi + (l * 2 + 0) * 16384, wf_lo + (l * 2 + 0) * 16384,
            wf_hi + (l * 2 + 1) * 16384, wf_lo + (l * 2 + 1) * 16384,
            b1 + l * HID, b2 + l * HID, gamma + l * HID, beta + l * HID);
        unsigned short* tmp = hbin; hbin = hbout; hbout = tmp;
    }
    // final h is in-place in `h` (fp32)

    k_pool<<<(N_NODES + 127) / 128, 128, 0, stream>>>(h, batch, sums, cnt);
    k_head<<<N_GRAPHS, 128, 0, stream>>>(sums, cnt, fcW1, fcb1, fcW2, fcb2,
                                         fcW3, fcb3, out);
}

// Round 9
// 789.710 us; speedup vs baseline: 5.1693x; 1.0587x over previous
//
#include <hip/hip_runtime.h>

#define N_NODES 100000
#define N_EDGES 1600000
#define N_GRAPHS 1024
#define HID 128
#define LAYERS 4
#define LN_EPS 1e-5f
#define NB_SCAN 391  // ceil(100000/256)
#define GTS 136      // ushort row stride for bf16 LDS planes (16B-aligned)
#define NB_PROJ 50000
#define NB_WCONV 512

typedef __attribute__((ext_vector_type(8))) short bf16x8;
typedef __attribute__((ext_vector_type(4))) float f32x4;

__device__ __forceinline__ unsigned short f2bf(float x) {
    unsigned v = __float_as_uint(x);
    return (unsigned short)((v + 0x7fffu + ((v >> 16) & 1u)) >> 16);
}
__device__ __forceinline__ float bfval(unsigned short u) {
    return __uint_as_float((unsigned)u << 16);
}

// ------- prep: input projection + MFMA weight pre-swizzle (fused) ----
__global__ __launch_bounds__(256) void k_prep(
    const float* __restrict__ x, const float* __restrict__ inW,
    const float* __restrict__ inb, float* __restrict__ h,
    unsigned short* __restrict__ hb,
    const float* __restrict__ w1, const float* __restrict__ w2,
    unsigned short* __restrict__ wf_hi, unsigned short* __restrict__ wf_lo) {
    if (blockIdx.x < NB_PROJ) {
        int idx = blockIdx.x * 256 + threadIdx.x;  // N_NODES*HID exact
        int n = idx >> 7, c = idx & 127;
        const float* xr = x + n * 7;
        float s = inb[c];
#pragma unroll
        for (int k = 0; k < 7; ++k) s += xr[k] * inW[k * HID + c];
        h[idx] = s;
        hb[idx] = f2bf(s);
    } else {
        int idx = (blockIdx.x - NB_PROJ) * 256 + threadIdx.x;  // LAYERS*2*16384
        int wid = idx >> 14;
        int layer = wid >> 1, which = wid & 1;
        int within = idx & 16383;
        int nt = within >> 11;
        int ks = (within >> 9) & 3;
        int ln = (within >> 3) & 63;
        int j = within & 7;
        const float* W = (which ? w2 : w1) + layer * HID * HID;
        int k = ks * 32 + (ln >> 4) * 8 + j;
        int n = nt * 16 + (ln & 15);
        float v = W[k * HID + n];
        unsigned short hi = f2bf(v);
        wf_hi[idx] = hi;
        wf_lo[idx] = f2bf(v - bfval(hi));
    }
}

// ---------------- CSR build: histogram of dst ------------------------
__global__ __launch_bounds__(256) void k_hist(
    const int* __restrict__ ei, int* __restrict__ deg) {
    int e = blockIdx.x * 256 + threadIdx.x;  // N_EDGES exact
    atomicAdd(&deg[ei[N_EDGES + e]], 1);
}

// ---------------- CSR build: parallel 3-stage scan -------------------
__global__ __launch_bounds__(256) void k_scan1(
    const int* __restrict__ deg, int* __restrict__ bsum) {
    const int i = blockIdx.x * 256 + threadIdx.x;
    int v = (i < N_NODES) ? deg[i] : 0;
#pragma unroll
    for (int off = 1; off < 64; off <<= 1) v += __shfl_xor(v, off);
    __shared__ int wsum[4];
    if ((threadIdx.x & 63) == 0) wsum[threadIdx.x >> 6] = v;
    __syncthreads();
    if (threadIdx.x == 0) bsum[blockIdx.x] = wsum[0] + wsum[1] + wsum[2] + wsum[3];
}

__global__ __launch_bounds__(512) void k_scan2(
    const int* __restrict__ bsum, int* __restrict__ bpre) {
    __shared__ int tmp[512];
    const int t = threadIdx.x;
    int v = (t < NB_SCAN) ? bsum[t] : 0;
    tmp[t] = v;
    __syncthreads();
    for (int off = 1; off < 512; off <<= 1) {
        int u = (t >= off) ? tmp[t - off] : 0;
        __syncthreads();
        tmp[t] += u;
        __syncthreads();
    }
    if (t < NB_SCAN) bpre[t] = tmp[t] - v;  // exclusive
}

__global__ __launch_bounds__(256) void k_scan3(
    const int* __restrict__ deg, const int* __restrict__ bpre,
    int* __restrict__ row_ptr, int* __restrict__ cursor) {
    __shared__ int tmp[256];
    const int t = threadIdx.x;
    const int i = blockIdx.x * 256 + t;
    int d = (i < N_NODES) ? deg[i] : 0;
    tmp[t] = d;
    __syncthreads();
    for (int off = 1; off < 256; off <<= 1) {
        int u = (t >= off) ? tmp[t - off] : 0;
        __syncthreads();
        tmp[t] += u;
        __syncthreads();
    }
    if (i < N_NODES) {
        const int ex = bpre[blockIdx.x] + tmp[t] - d;
        row_ptr[i] = ex;
        cursor[i] = ex;
        if (i == N_NODES - 1) row_ptr[N_NODES] = N_EDGES;
    }
}

// ---------------- CSR build: scatter edges into sorted slots ---------
__global__ __launch_bounds__(256) void k_scatter(
    const int* __restrict__ ei, const float* __restrict__ ea,
    int* __restrict__ cursor, float4* __restrict__ edata) {
    int e = blockIdx.x * 256 + threadIdx.x;  // N_EDGES exact
    const int src = ei[e];
    const int dst = ei[N_EDGES + e];
    const int pos = atomicAdd(&cursor[dst], 1);
    edata[pos] = make_float4(ea[e * 3 + 0], ea[e * 3 + 1], ea[e * 3 + 2],
                             __int_as_float(src));
}

// -- phase-1 edge macros (macros only: outlined helpers spill, R4/R5) --
// EL: ds_read_b32 of src field -> scalar base -> 4B bf16x2 gather.
// EC: ds_read_b128 of attrs, project, relu, scalar row select.
#define EL(JJ)                                                                 \
    const int s##JJ = __builtin_amdgcn_readfirstlane(                          \
        __float_as_int(etile[wbase + (j + JJ) * 4 + 3]));                      \
    const unsigned gq##JJ = *(const unsigned*)(hbin + (long)s##JJ * HID + c2);

#define EC(JJ) {                                                               \
    const float4 ed = *(const float4*)&etile[wbase + (j + JJ) * 4];            \
    const float gx = __uint_as_float(gq##JJ << 16) + ebv.x;                    \
    const float gy = __uint_as_float(gq##JJ & 0xffff0000u) + ebv.y;            \
    const float mx = fmaxf(fmaf(ed.z, ew2.x, fmaf(ed.y, ew1.x,                 \
                     fmaf(ed.x, ew0.x, gx))), 0.f);                            \
    const float my = fmaxf(fmaf(ed.z, ew2.y, fmaf(ed.y, ew1.y,                 \
                     fmaf(ed.x, ew0.y, gy))), 0.f);                            \
    const int gi = t + j + (JJ);                                               \
    if (gi < rp1)      { a0x += mx; a0y += my; }                               \
    else if (gi < rp2) { a1x += mx; a1y += my; }                               \
    else if (gi < rp3) { a2x += mx; a2y += my; }                               \
    else               { a3x += mx; a3y += my; } }

#define ROW_OUT(R, AX, AY) {                                                   \
    const float2 hv = *(const float2*)(h + (long)(nb + (R)) * HID + c2);       \
    const float gx = hv.x + (AX), gy = hv.y + (AY);                            \
    const unsigned short hx = f2bf(gx), hy = f2bf(gy);                         \
    const unsigned short lx = f2bf(gx - bfval(hx)), ly = f2bf(gy - bfval(hy)); \
    *(unsigned*)&gt_hi[(r0 + (R)) * GTS + c2] = (unsigned)hx | ((unsigned)hy << 16); \
    *(unsigned*)&gt_lo[(r0 + (R)) * GTS + c2] = (unsigned)lx | ((unsigned)ly << 16); }

#define T1_OUT(CC, NT) {                                                       \
    const float4 bv = *(const float4*)(b1 + (NT) * 16 + q4);                   \
    const float v0 = fmaxf(CC[0] + bv.x, 0.f);                                 \
    const float v1 = fmaxf(CC[1] + bv.y, 0.f);                                 \
    const float v2 = fmaxf(CC[2] + bv.z, 0.f);                                 \
    const float v3 = fmaxf(CC[3] + bv.w, 0.f);                                 \
    const unsigned short h0_ = f2bf(v0), h1_ = f2bf(v1), h2_ = f2bf(v2), h3_ = f2bf(v3); \
    const unsigned short l0_ = f2bf(v0 - bfval(h0_)), l1_ = f2bf(v1 - bfval(h1_)); \
    const unsigned short l2_ = f2bf(v2 - bfval(h2_)), l3_ = f2bf(v3 - bfval(h3_)); \
    *(uint2*)&t1_hi[ln15 * GTS + (NT) * 16 + q4] =                             \
        make_uint2((unsigned)h0_ | ((unsigned)h1_ << 16), (unsigned)h2_ | ((unsigned)h3_ << 16)); \
    *(uint2*)&t1_lo[ln15 * GTS + (NT) * 16 + q4] =                             \
        make_uint2((unsigned)l0_ | ((unsigned)l1_ << 16), (unsigned)l2_ | ((unsigned)l3_ << 16)); }

// ------- fused gather-aggregate + MFMA MLP + residual + layernorm ----
// 256 threads = 4 waves, 16 nodes/block. Phase 1: full wave per edge,
// scalar row select, 16 bf16 gathers in flight + register tile prefetch.
// GEMMs: mfma_f32_16x16x32_bf16, hi/lo split both operands (3-MFMA).
// LN: register u + 2-shfl partials + 512B LDS stats (no u_buf).
__global__ __launch_bounds__(256, 6) void k_node_update(
    const float4* __restrict__ edata, const int* __restrict__ row_ptr,
    const float* __restrict__ eW, const float* __restrict__ eb,
    float* __restrict__ h, const unsigned short* __restrict__ hbin,
    unsigned short* __restrict__ hbout,
    const unsigned short* __restrict__ w1f_hi, const unsigned short* __restrict__ w1f_lo,
    const unsigned short* __restrict__ w2f_hi, const unsigned short* __restrict__ w2f_lo,
    const float* __restrict__ b1, const float* __restrict__ b2,
    const float* __restrict__ gamma, const float* __restrict__ beta) {
    __shared__ __align__(16) unsigned char smem[21504];
    float* etile = (float*)smem;                              // [4][256] f32, phase 1
    float* stats = (float*)smem;                              // [4][32] f32, phase 3 (alias)
    unsigned short* gt_hi = (unsigned short*)(smem + 4096);   // [16][GTS]
    unsigned short* gt_lo = (unsigned short*)(smem + 8448);
    unsigned short* t1_hi = (unsigned short*)(smem + 12800);
    unsigned short* t1_lo = (unsigned short*)(smem + 17152);

    const int wave = threadIdx.x >> 6;
    const int lane = threadIdx.x & 63;
    const int n0 = blockIdx.x * 16;
    const int r0 = wave * 4;
    const int c2 = lane * 2;
    const int wbase = wave * 256;

    // ---- phase 1: gather-aggregate, full wave per edge ----
    {
        const float2 ew0 = *(const float2*)(eW + 0 * HID + c2);
        const float2 ew1 = *(const float2*)(eW + 1 * HID + c2);
        const float2 ew2 = *(const float2*)(eW + 2 * HID + c2);
        const float2 ebv = *(const float2*)(eb + c2);
        const int nb = n0 + r0;
        const int rp0 = __builtin_amdgcn_readfirstlane(row_ptr[nb + 0]);
        const int rp1 = __builtin_amdgcn_readfirstlane(row_ptr[nb + 1]);
        const int rp2 = __builtin_amdgcn_readfirstlane(row_ptr[nb + 2]);
        const int rp3 = __builtin_amdgcn_readfirstlane(row_ptr[nb + 3]);
        const int rp4 = __builtin_amdgcn_readfirstlane(row_ptr[nb + 4]);

        float a0x = 0.f, a0y = 0.f, a1x = 0.f, a1y = 0.f;
        float a2x = 0.f, a2y = 0.f, a3x = 0.f, a3y = 0.f;

        float4 cur;
        if (rp0 + lane < rp4) cur = edata[rp0 + lane];
        for (int t = rp0; t < rp4; t += 64) {
            const int cnt = (rp4 - t < 64) ? (rp4 - t) : 64;
            if (lane < cnt)
                *(float4*)&etile[wbase + lane * 4] = cur;
            if (t + 64 + lane < rp4) cur = edata[t + 64 + lane];  // prefetch next tile
            // same-wave LDS produce/consume: hardware-ordered, no barrier
            int j = 0;
            for (; j + 16 <= cnt; j += 16) {
                EL(0) EL(1) EL(2) EL(3) EL(4) EL(5) EL(6) EL(7)
                EL(8) EL(9) EL(10) EL(11) EL(12) EL(13) EL(14) EL(15)
                EC(0) EC(1) EC(2) EC(3) EC(4) EC(5) EC(6) EC(7)
                EC(8) EC(9) EC(10) EC(11) EC(12) EC(13) EC(14) EC(15)
            }
            for (; j + 4 <= cnt; j += 4) {
                EL(0) EL(1) EL(2) EL(3)
                EC(0) EC(1) EC(2) EC(3)
            }
            for (; j < cnt; ++j) {
                EL(0)
                EC(0)
            }
        }
        ROW_OUT(0, a0x, a0y)
        ROW_OUT(1, a1x, a1y)
        ROW_OUT(2, a2x, a2y)
        ROW_OUT(3, a3x, a3y)
    }
    __syncthreads();

    const int ln15 = lane & 15;
    const int q8 = (lane >> 4) * 8;
    const int q4 = (lane >> 4) * 4;
    const int nt0 = wave * 2, nt1 = nt0 + 1;

    // ---- phase 2: t1 = relu(gt @ w1 + b1) via MFMA (D[hid][node]) ----
    {
        f32x4 c0 = {0.f, 0.f, 0.f, 0.f};
        f32x4 c1 = {0.f, 0.f, 0.f, 0.f};
#pragma unroll
        for (int ks = 0; ks < 4; ++ks) {
            const bf16x8 bh = *(const bf16x8*)&gt_hi[ln15 * GTS + ks * 32 + q8];
            const bf16x8 bl = *(const bf16x8*)&gt_lo[ln15 * GTS + ks * 32 + q8];
            const bf16x8 a0h = *(const bf16x8*)(w1f_hi + (((nt0 * 4 + ks) * 64 + lane) << 3));
            const bf16x8 a0l = *(const bf16x8*)(w1f_lo + (((nt0 * 4 + ks) * 64 + lane) << 3));
            const bf16x8 a1h = *(const bf16x8*)(w1f_hi + (((nt1 * 4 + ks) * 64 + lane) << 3));
            const bf16x8 a1l = *(const bf16x8*)(w1f_lo + (((nt1 * 4 + ks) * 64 + lane) << 3));
            c0 = __builtin_amdgcn_mfma_f32_16x16x32_bf16(a0h, bh, c0, 0, 0, 0);
            c0 = __builtin_amdgcn_mfma_f32_16x16x32_bf16(a0h, bl, c0, 0, 0, 0);
            c0 = __builtin_amdgcn_mfma_f32_16x16x32_bf16(a0l, bh, c0, 0, 0, 0);
            c1 = __builtin_amdgcn_mfma_f32_16x16x32_bf16(a1h, bh, c1, 0, 0, 0);
            c1 = __builtin_amdgcn_mfma_f32_16x16x32_bf16(a1h, bl, c1, 0, 0, 0);
            c1 = __builtin_amdgcn_mfma_f32_16x16x32_bf16(a1l, bh, c1, 0, 0, 0);
        }
        T1_OUT(c0, nt0)
        T1_OUT(c1, nt1)
    }
    __syncthreads();

    // ---- phase 3: u = h + relu(t1 @ w2 + b2) in regs; fused LN ----
    {
        f32x4 c0 = {0.f, 0.f, 0.f, 0.f};
        f32x4 c1 = {0.f, 0.f, 0.f, 0.f};
#pragma unroll
        for (int ks = 0; ks < 4; ++ks) {
            const bf16x8 bh = *(const bf16x8*)&t1_hi[ln15 * GTS + ks * 32 + q8];
            const bf16x8 bl = *(const bf16x8*)&t1_lo[ln15 * GTS + ks * 32 + q8];
            const bf16x8 a0h = *(const bf16x8*)(w2f_hi + (((nt0 * 4 + ks) * 64 + lane) << 3));
            const bf16x8 a0l = *(const bf16x8*)(w2f_lo + (((nt0 * 4 + ks) * 64 + lane) << 3));
            const bf16x8 a1h = *(const bf16x8*)(w2f_hi + (((nt1 * 4 + ks) * 64 + lane) << 3));
            const bf16x8 a1l = *(const bf16x8*)(w2f_lo + (((nt1 * 4 + ks) * 64 + lane) << 3));
            c0 = __builtin_amdgcn_mfma_f32_16x16x32_bf16(a0h, bh, c0, 0, 0, 0);
            c0 = __builtin_amdgcn_mfma_f32_16x16x32_bf16(a0h, bl, c0, 0, 0, 0);
            c0 = __builtin_amdgcn_mfma_f32_16x16x32_bf16(a0l, bh, c0, 0, 0, 0);
            c1 = __builtin_amdgcn_mfma_f32_16x16x32_bf16(a1h, bh, c1, 0, 0, 0);
            c1 = __builtin_amdgcn_mfma_f32_16x16x32_bf16(a1h, bl, c1, 0, 0, 0);
            c1 = __builtin_amdgcn_mfma_f32_16x16x32_bf16(a1l, bh, c1, 0, 0, 0);
        }
        const int row = n0 + ln15;
        const float4 b20 = *(const float4*)(b2 + nt0 * 16 + q4);
        const float4 b21 = *(const float4*)(b2 + nt1 * 16 + q4);
        const float4 hv0 = *(const float4*)(h + (long)row * HID + nt0 * 16 + q4);
        const float4 hv1 = *(const float4*)(h + (long)row * HID + nt1 * 16 + q4);
        float4 u0, u1;
        u0.x = hv0.x + fmaxf(c0[0] + b20.x, 0.f);
        u0.y = hv0.y + fmaxf(c0[1] + b20.y, 0.f);
        u0.z = hv0.z + fmaxf(c0[2] + b20.z, 0.f);
        u0.w = hv0.w + fmaxf(c0[3] + b20.w, 0.f);
        u1.x = hv1.x + fmaxf(c1[0] + b21.x, 0.f);
        u1.y = hv1.y + fmaxf(c1[1] + b21.y, 0.f);
        u1.z = hv1.z + fmaxf(c1[2] + b21.z, 0.f);
        u1.w = hv1.w + fmaxf(c1[3] + b21.w, 0.f);
        float s = u0.x + u0.y + u0.z + u0.w + u1.x + u1.y + u1.z + u1.w;
        float s2 = u0.x * u0.x + u0.y * u0.y + u0.z * u0.z + u0.w * u0.w +
                   u1.x * u1.x + u1.y * u1.y + u1.z * u1.z + u1.w * u1.w;
        s += __shfl_xor(s, 16); s2 += __shfl_xor(s2, 16);
        s += __shfl_xor(s, 32); s2 += __shfl_xor(s2, 32);
        if (lane < 16) {
            stats[wave * 32 + lane * 2 + 0] = s;
            stats[wave * 32 + lane * 2 + 1] = s2;
        }
        __syncthreads();
        const float S  = stats[0 * 32 + ln15 * 2] + stats[1 * 32 + ln15 * 2] +
                         stats[2 * 32 + ln15 * 2] + stats[3 * 32 + ln15 * 2];
        const float S2 = stats[0 * 32 + ln15 * 2 + 1] + stats[1 * 32 + ln15 * 2 + 1] +
                         stats[2 * 32 + ln15 * 2 + 1] + stats[3 * 32 + ln15 * 2 + 1];
        const float mu = S * (1.f / HID);
        const float var = S2 * (1.f / HID) - mu * mu;
        const float inv = rsqrtf(var + LN_EPS);
        const float4 gm0 = *(const float4*)(gamma + nt0 * 16 + q4);
        const float4 gm1 = *(const float4*)(gamma + nt1 * 16 + q4);
        const float4 bt0 = *(const float4*)(beta + nt0 * 16 + q4);
        const float4 bt1 = *(const float4*)(beta + nt1 * 16 + q4);
        float4 o0, o1;
        o0.x = (u0.x - mu) * inv * gm0.x + bt0.x;
        o0.y = (u0.y - mu) * inv * gm0.y + bt0.y;
        o0.z = (u0.z - mu) * inv * gm0.z + bt0.z;
        o0.w = (u0.w - mu) * inv * gm0.w + bt0.w;
        o1.x = (u1.x - mu) * inv * gm1.x + bt1.x;
        o1.y = (u1.y - mu) * inv * gm1.y + bt1.y;
        o1.z = (u1.z - mu) * inv * gm1.z + bt1.z;
        o1.w = (u1.w - mu) * inv * gm1.w + bt1.w;
        *(float4*)(h + (long)row * HID + nt0 * 16 + q4) = o0;
        *(float4*)(h + (long)row * HID + nt1 * 16 + q4) = o1;
        *(uint2*)(hbout + (long)row * HID + nt0 * 16 + q4) =
            make_uint2((unsigned)f2bf(o0.x) | ((unsigned)f2bf(o0.y) << 16),
                       (unsigned)f2bf(o0.z) | ((unsigned)f2bf(o0.w) << 16));
        *(uint2*)(hbout + (long)row * HID + nt1 * 16 + q4) =
            make_uint2((unsigned)f2bf(o1.x) | ((unsigned)f2bf(o1.y) << 16),
                       (unsigned)f2bf(o1.z) | ((unsigned)f2bf(o1.w) << 16));
    }
}

// -------- global mean pool: segmented reduction (batch is sorted) ----
__global__ __launch_bounds__(128) void k_pool(
    const float* __restrict__ h, const int* __restrict__ batch,
    float* __restrict__ sums, float* __restrict__ cnt) {
    const int c = threadIdx.x;
    const int n0 = blockIdx.x * 64;
    if (n0 >= N_NODES) return;
    const int nend = min(n0 + 64, N_NODES);
    int cur = batch[n0];
    float acc = 0.f;
    int runlen = 0;
    for (int n = n0; n < nend; ++n) {
        const int b = batch[n];
        if (b != cur) {
            atomicAdd(&sums[(long)cur * HID + c], acc);
            if (c == 0) atomicAdd(&cnt[cur], (float)runlen);
            acc = 0.f;
            runlen = 0;
            cur = b;
        }
        acc += h[(long)n * HID + c];
        ++runlen;
    }
    atomicAdd(&sums[(long)cur * HID + c], acc);
    if (c == 0) atomicAdd(&cnt[cur], (float)runlen);
}

// ---------------- head: 1 block per graph ----------------------------
__global__ __launch_bounds__(128) void k_head(
    const float* __restrict__ sums, const float* __restrict__ cnt,
    const float* __restrict__ fcW1, const float* __restrict__ fcb1,
    const float* __restrict__ fcW2, const float* __restrict__ fcb2,
    const float* __restrict__ fcW3, const float* __restrict__ fcb3,
    float* __restrict__ out) {
    __shared__ float p[HID];
    __shared__ float o1[HID];
    __shared__ float o2[64];
    const int g = blockIdx.x, t = threadIdx.x;
    const float c = fmaxf(cnt[g], 1.0f);
    p[t] = sums[g * HID + t] / c;
    __syncthreads();
    float s = fcb1[t];
    for (int k = 0; k < HID; ++k) s += p[k] * fcW1[k * HID + t];
    o1[t] = fmaxf(s, 0.f);
    __syncthreads();
    if (t < 64) {
        float s2 = fcb2[t];
        for (int k = 0; k < HID; ++k) s2 += o1[k] * fcW2[k * 64 + t];
        o2[t] = fmaxf(s2, 0.f);
    }
    __syncthreads();
    if (t < 64) {
        float v = o2[t] * fcW3[t];
#pragma unroll
        for (int off = 32; off > 0; off >>= 1) v += __shfl_down(v, off);
        if (t == 0) out[g] = v + fcb3[0];
    }
}

extern "C" void kernel_launch(void* const* d_in, const int* in_sizes, int n_in,
                              void* d_out, int out_size, void* d_ws, size_t ws_size,
                              hipStream_t stream) {
    const float* x    = (const float*)d_in[0];
    const int*   ei   = (const int*)d_in[1];
    const float* ea   = (const float*)d_in[2];
    const int*   batch= (const int*)d_in[3];
    const float* inW  = (const float*)d_in[4];
    const float* inb  = (const float*)d_in[5];
    const float* edgeW= (const float*)d_in[6];
    const float* edgeb= (const float*)d_in[7];
    const float* w1   = (const float*)d_in[8];
    const float* b1   = (const float*)d_in[9];
    const float* w2   = (const float*)d_in[10];
    const float* b2   = (const float*)d_in[11];
    const float* gamma= (const float*)d_in[12];
    const float* beta = (const float*)d_in[13];
    const float* fcW1 = (const float*)d_in[14];
    const float* fcb1 = (const float*)d_in[15];
    const float* fcW2 = (const float*)d_in[16];
    const float* fcb2 = (const float*)d_in[17];
    const float* fcW3 = (const float*)d_in[18];
    const float* fcb3 = (const float*)d_in[19];
    float* out = (float*)d_out;

    // workspace layout (16B-aligned blocks first): ~129 MB
    float4* edata = (float4*)d_ws;                                     // 25.6 MB
    float*  h     = (float*)(edata + N_EDGES);                         // 51.2 MB
    unsigned short* hb0 = (unsigned short*)(h + (size_t)N_NODES * HID);// 25.6 MB
    unsigned short* hb1 = hb0 + (size_t)N_NODES * HID;                 // 25.6 MB
    unsigned short* wf_hi = hb1 + (size_t)N_NODES * HID;               // 256 KB
    unsigned short* wf_lo = wf_hi + LAYERS * 2 * 16384;                // 256 KB
    int*    row_ptr = (int*)(wf_lo + LAYERS * 2 * 16384);              // 100001
    int*    cursor  = row_ptr + (N_NODES + 1);
    int*    deg     = cursor + N_NODES;
    int*    bsum    = deg + N_NODES;
    int*    bpre    = bsum + 512;
    float*  sums    = (float*)(bpre + 512);
    float*  cnt     = sums + (size_t)N_GRAPHS * HID;

    hipMemsetAsync(deg, 0, N_NODES * sizeof(int), stream);
    hipMemsetAsync(sums, 0, ((size_t)N_GRAPHS * HID + N_GRAPHS) * sizeof(float), stream);

    k_prep<<<NB_PROJ + NB_WCONV, 256, 0, stream>>>(x, inW, inb, h, hb0,
                                                   w1, w2, wf_hi, wf_lo);

    // CSR build (once per launch, reused across 4 layers)
    k_hist<<<N_EDGES / 256, 256, 0, stream>>>(ei, deg);
    k_scan1<<<NB_SCAN, 256, 0, stream>>>(deg, bsum);
    k_scan2<<<1, 512, 0, stream>>>(bsum, bpre);
    k_scan3<<<NB_SCAN, 256, 0, stream>>>(deg, bpre, row_ptr, cursor);
    k_scatter<<<N_EDGES / 256, 256, 0, stream>>>(ei, ea, cursor, edata);

    unsigned short* hbin = hb0;
    unsigned short* hbout = hb1;
    for (int l = 0; l < LAYERS; ++l) {
        k_node_update<<<N_NODES / 16, 256, 0, stream>>>(
            edata, row_ptr, edgeW + l * 3 * HID, edgeb + l * HID,
            h, hbin, hbout,
            wf_hi + (l * 2 + 0) * 16384, wf_lo + (l * 2 + 0) * 16384,
            wf_hi + (l * 2 + 1) * 16384, wf_lo + (l * 2 + 1) * 16384,
            b1 + l * HID, b2 + l * HID, gamma + l * HID, beta + l * HID);
        unsigned short* tmp = hbin; hbin = hbout; hbout = tmp;
    }
    // final h is in-place in `h` (fp32)

    k_pool<<<(N_NODES + 63) / 64, 128, 0, stream>>>(h, batch, sums, cnt);
    k_head<<<N_GRAPHS, 128, 0, stream>>>(sums, cnt, fcW1, fcb1, fcW2, fcb2,
                                         fcW3, fcb3, out);
}